// Round 6
// baseline (323.260 us; speedup 1.0000x reference)
//
#include <hip/hip_runtime.h>

#define BB   8
#define NN   4096
#define CIN  64
#define COUT 128
#define KNN  16
#define NTOT (BB * NN)

typedef _Float16 half8 __attribute__((ext_vector_type(8)));
typedef float f32x4 __attribute__((ext_vector_type(4)));
typedef unsigned short u16x8 __attribute__((ext_vector_type(8)));

// bitonic sort 16 ascending, fully unrolled (all reg indices compile-time)
__device__ __forceinline__ void bitonic_sort16(unsigned a[16]) {
#pragma unroll
    for (int kk = 2; kk <= 16; kk <<= 1) {
#pragma unroll
        for (int jj = kk >> 1; jj > 0; jj >>= 1) {
#pragma unroll
            for (int i = 0; i < 16; ++i) {
                int l = i ^ jj;
                if (l > i) {
                    unsigned lo = a[i] < a[l] ? a[i] : a[l];
                    unsigned hi = a[i] < a[l] ? a[l] : a[i];
                    if ((i & kk) == 0) { a[i] = lo; a[l] = hi; }
                    else               { a[i] = hi; a[l] = lo; }
                }
            }
        }
    }
}

// ---------------------------------------------------------------------------
// Kernel 1: fused per-point squared norm + fp32->fp16 conversion.
// ---------------------------------------------------------------------------
__global__ __launch_bounds__(256) void prep_kernel(
    const float* __restrict__ x, float* __restrict__ sq, _Float16* __restrict__ xh)
{
    int i = blockIdx.x * 256 + threadIdx.x;            // point id
    const float4* xr = (const float4*)(x + (size_t)i * CIN);
    half8* xw = (half8*)(xh + (size_t)i * CIN);
    float s0 = 0.f, s1 = 0.f;
#pragma unroll
    for (int j = 0; j < 8; ++j) {
        float4 a = xr[2 * j], b = xr[2 * j + 1];
        s0 = fmaf(a.x, a.x, s0); s0 = fmaf(a.y, a.y, s0);
        s0 = fmaf(a.z, a.z, s0); s0 = fmaf(a.w, a.w, s0);
        s1 = fmaf(b.x, b.x, s1); s1 = fmaf(b.y, b.y, s1);
        s1 = fmaf(b.z, b.z, s1); s1 = fmaf(b.w, b.w, s1);
        half8 h;
        h[0] = (_Float16)a.x; h[1] = (_Float16)a.y;
        h[2] = (_Float16)a.z; h[3] = (_Float16)a.w;
        h[4] = (_Float16)b.x; h[5] = (_Float16)b.y;
        h[6] = (_Float16)b.z; h[7] = (_Float16)b.w;
        xw[j] = h;
    }
    sq[i] = s0 + s1;
}

// ---------------------------------------------------------------------------
// Kernel 2: MFMA kNN scan. Grid = 512 tiles x 2 halves. Per 64-cand chunk:
// dbuf-staged fp16 candidates -> MFMA 64x64 dots -> packed keys
// (trunc-dist|id) into s_key (stride 66, b64-readable) -> per-thread
// bitonic-sort-16 + merge into register sorted best-16. 2 barriers/chunk.
// Writes lowest 12 keys per (point, half, strip) — same contract as R5.
// ---------------------------------------------------------------------------
__global__ __launch_bounds__(256) void knn_scan_mfma_kernel(
    const _Float16* __restrict__ xh, const float* __restrict__ sq,
    unsigned* __restrict__ sub_k)
{
    __shared__ _Float16 sBT[2][8][64][8];  // 16 KB dbuf [buf][k-granule][cand][8]
    __shared__ unsigned s_key[64 * 66];    // 16.5 KB [row][col] stride 66
    __shared__ float    s_sqm[2][64];

    int blk  = blockIdx.x;
    int tile = blk >> 1;
    int half = blk & 1;
    int b    = tile >> 6;
    int n0   = (tile & 63) * 64;
    int t    = threadIdx.x;
    int l    = t & 63;
    int w    = t >> 6;                     // wave id -> MFMA row strip / select strip
    int quad = l >> 4;
    int c16  = l & 15;
    int p    = l;                          // selection point
    int q    = w;                          // selection col strip

    const _Float16* xhb = xh + (size_t)b * NN * CIN;
    const float*    sqb = sq + (size_t)b * NN;

    // epilogue rows for this lane are chunk-invariant: preload sqn into regs
    float sqn_r[4];
#pragma unroll
    for (int r = 0; r < 4; ++r)
        sqn_r[r] = sqb[n0 + 16 * w + 4 * quad + r];

    // A fragments: A[m = 16w + c16][k = s*32 + quad*8 + j]
    int row_a = n0 + 16 * w + c16;
    half8 afrag0 = *(const half8*)(xhb + (size_t)row_a * CIN + 0 * 32 + quad * 8);
    half8 afrag1 = *(const half8*)(xhb + (size_t)row_a * CIN + 1 * 32 + quad * 8);

    unsigned best[16];
#pragma unroll
    for (int j = 0; j < 16; ++j) best[j] = 0xFFFFFFFFu;

    // stage chunk 0 into buf 0
    {
        int cb0 = half * 2048;
#pragma unroll
        for (int r2 = 0; r2 < 2; ++r2) {
            int f = r2 * 256 + t;
            int cand = f >> 3, g = f & 7;
            *(half8*)&sBT[0][g][cand][0] =
                *(const half8*)(xhb + (size_t)(cb0 + cand) * CIN + g * 8);
        }
        if (t < 64) s_sqm[0][t] = sqb[cb0 + t];
    }

#pragma unroll 1
    for (int c = 0; c < 32; ++c) {
        int cur = c & 1;
        int cbase = half * 2048 + c * 64;
        __syncthreads();                   // staging for c done; s_key free

        // prefetch chunk c+1 to regs (hidden behind MFMA)
        half8 st0, st1; float sqm_n = 0.f;
        int cand0 = t >> 3, g0 = t & 7;
        int cand1 = (256 + t) >> 3, g1 = t & 7;
        bool do_stage = (c < 31);
        if (do_stage) {
            int cb_n = cbase + 64;
            st0 = *(const half8*)(xhb + (size_t)(cb_n + cand0) * CIN + g0 * 8);
            st1 = *(const half8*)(xhb + (size_t)(cb_n + cand1) * CIN + g1 * 8);
            if (t < 64) sqm_n = sqb[cb_n + t];
        }

        // MFMA: wave w computes rows [16w,16w+16) x 64 cols
        f32x4 acc[4];
#pragma unroll
        for (int n = 0; n < 4; ++n) acc[n] = (f32x4){0.f, 0.f, 0.f, 0.f};
#pragma unroll
        for (int n = 0; n < 4; ++n) {
            half8 b0 = *(const half8*)&sBT[cur][0 * 4 + quad][16 * n + c16][0];
            half8 b1 = *(const half8*)&sBT[cur][1 * 4 + quad][16 * n + c16][0];
            acc[n] = __builtin_amdgcn_mfma_f32_16x16x32_f16(afrag0, b0, acc[n], 0, 0, 0);
            acc[n] = __builtin_amdgcn_mfma_f32_16x16x32_f16(afrag1, b1, acc[n], 0, 0, 0);
        }

        // write staged regs into the other buffer (no barrier needed: dbuf)
        if (do_stage) {
            *(half8*)&sBT[cur ^ 1][g0][cand0][0] = st0;
            *(half8*)&sBT[cur ^ 1][g1][cand1][0] = st1;
            if (t < 64) s_sqm[cur ^ 1][t] = sqm_n;
        }

        // epilogue: dist = max(sqn + sqm - 2*dot, 0); pack (trunc|id)
#pragma unroll
        for (int n = 0; n < 4; ++n) {
            int col = 16 * n + c16;
            float sm = s_sqm[cur][col];
            unsigned id = (unsigned)(cbase + col);
#pragma unroll
            for (int r = 0; r < 4; ++r) {
                int row = 16 * w + 4 * quad + r;
                float d = fmaxf(sqn_r[r] + sm - 2.0f * acc[n][r], 0.0f);
                s_key[row * 66 + col] = (__float_as_uint(d) & 0xFFFFF000u) | id;
            }
        }
        __syncthreads();                   // s_key ready

        // selection: load 16 keys (b64), bitonic sort, merge into best-16
        unsigned a16[16];
#pragma unroll
        for (int j = 0; j < 8; ++j) {
            uint2 v = *(const uint2*)&s_key[p * 66 + q * 16 + 2 * j];
            a16[2 * j] = v.x; a16[2 * j + 1] = v.y;
        }
        bitonic_sort16(a16);
        unsigned m16[16];
#pragma unroll
        for (int i = 0; i < 16; ++i)
            m16[i] = best[i] < a16[15 - i] ? best[i] : a16[15 - i];
#pragma unroll
        for (int d = 8; d > 0; d >>= 1) {
#pragma unroll
            for (int i = 0; i < 16; ++i) {
                if ((i & d) == 0) {
                    unsigned xx = m16[i], yy = m16[i | d];
                    unsigned lo = xx < yy ? xx : yy;
                    unsigned hi = xx < yy ? yy : xx;
                    m16[i] = lo; m16[i | d] = hi;
                }
            }
        }
#pragma unroll
        for (int i = 0; i < 16; ++i) best[i] = m16[i];
    }

    // write lowest 12 keys: [point][half*4+q][12]
    size_t base = (((size_t)b * NN + n0 + p) * 8 + half * 4 + q) * 12;
    uint4* dst = (uint4*)(sub_k + base);
    dst[0] = make_uint4(best[0], best[1], best[2],  best[3]);
    dst[1] = make_uint4(best[4], best[5], best[6],  best[7]);
    dst[2] = make_uint4(best[8], best[9], best[10], best[11]);
}

// ---------------------------------------------------------------------------
// Kernel 3: rescue + gather + max-pool (unchanged from R5, key-pruned exact).
// ---------------------------------------------------------------------------
__global__ __launch_bounds__(256) void rescue_pool_kernel(
    const float* __restrict__ x, const float* __restrict__ sq,
    const unsigned* __restrict__ sub_k, float* __restrict__ pooled)
{
    __shared__ unsigned s_pk[4][64][17];
    __shared__ unsigned short s_cand[64][26];
    __shared__ unsigned long long s_ek[4][64][6];
    __shared__ int s_out[64][KNN];

    int blk = blockIdx.x;
    int b   = blk >> 6;
    int n0  = (blk & 63) * 64;
    int t   = threadIdx.x;
    int p   = t & 63;
    int sub = t >> 6;
    const float* xb  = x  + (size_t)b * NN * CIN;
    const float* sqb = sq + (size_t)b * NN;
    size_t gp = (size_t)b * NN + n0 + p;

    float xn[CIN];
    {
        const float4* xr = (const float4*)(xb + (size_t)(n0 + p) * CIN);
#pragma unroll
        for (int j = 0; j < CIN / 4; ++j) {
            float4 v = xr[j];
            xn[4 * j + 0] = v.x; xn[4 * j + 1] = v.y;
            xn[4 * j + 2] = v.z; xn[4 * j + 3] = v.w;
        }
    }
    float sqn = sqb[n0 + p];

    // P1: CE 24 approx keys -> sorted top-16
    {
        unsigned bk[16];
#pragma unroll
        for (int j = 0; j < 16; ++j) bk[j] = 0xFFFFFFFFu;
        const uint4* kp = (const uint4*)(sub_k + gp * 96 + sub * 24);
#pragma unroll
        for (int j = 0; j < 6; ++j) {
            uint4 kv = kp[j];
            unsigned kk[4] = { kv.x, kv.y, kv.z, kv.w };
#pragma unroll
            for (int e = 0; e < 4; ++e) {
                unsigned cur = kk[e];
#pragma unroll
                for (int s = 0; s < 16; ++s) {
                    unsigned lo = bk[s] < cur ? bk[s] : cur;
                    unsigned hi = bk[s] < cur ? cur : bk[s];
                    bk[s] = lo; cur = hi;
                }
            }
        }
#pragma unroll
        for (int j = 0; j < 16; ++j) s_pk[sub][p][j] = bk[j];
    }
    __syncthreads();

    // P2: 4-way merge -> top-24 ids
    if (t < 64) {
        int p0 = 0, p1 = 0, p2 = 0, p3 = 0;
#pragma unroll 1
        for (int k = 0; k < 24; ++k) {
            unsigned k0 = (p0 < 16) ? s_pk[0][t][p0] : 0xFFFFFFFFu;
            unsigned k1 = (p1 < 16) ? s_pk[1][t][p1] : 0xFFFFFFFFu;
            unsigned k2 = (p2 < 16) ? s_pk[2][t][p2] : 0xFFFFFFFFu;
            unsigned k3 = (p3 < 16) ? s_pk[3][t][p3] : 0xFFFFFFFFu;
            unsigned bk = k0; int bq = 0;
            if (k1 < bk) { bk = k1; bq = 1; }
            if (k2 < bk) { bk = k2; bq = 2; }
            if (k3 < bk) { bk = k3; bq = 3; }
            s_cand[t][k] = (unsigned short)(bk & 0xFFFu);
            if (bq == 0) ++p0; else if (bq == 1) ++p1; else if (bq == 2) ++p2; else ++p3;
        }
    }
    __syncthreads();

    // P3: exact fp32 distances for 6 ids/thread, reference-faithful 64-bit keys
    {
        unsigned long long b6[6];
#pragma unroll
        for (int j = 0; j < 6; ++j) b6[j] = ~0ULL;
#pragma unroll 1
        for (int j = 0; j < 6; ++j) {
            int m = s_cand[p][sub * 6 + j];
            const float4* xm4 = (const float4*)(xb + (size_t)m * CIN);
            float d0 = 0.f, d1 = 0.f, d2 = 0.f, d3 = 0.f;
#pragma unroll
            for (int cc = 0; cc < CIN / 4; ++cc) {
                float4 v = xm4[cc];
                d0 = fmaf(xn[4 * cc + 0], v.x, d0);
                d1 = fmaf(xn[4 * cc + 1], v.y, d1);
                d2 = fmaf(xn[4 * cc + 2], v.z, d2);
                d3 = fmaf(xn[4 * cc + 3], v.w, d3);
            }
            float d = sqn + sqb[m] - 2.0f * ((d0 + d1) + (d2 + d3));
            unsigned bbits = __float_as_uint(d);
            unsigned sgn   = (unsigned)((int)bbits >> 31);
            unsigned u     = bbits ^ (sgn | 0x80000000u);
            unsigned long long cur = ((unsigned long long)u << 32) | (unsigned)m;
#pragma unroll
            for (int s = 0; s < 6; ++s) {
                unsigned long long lo = cur < b6[s] ? cur : b6[s];
                unsigned long long hi = cur < b6[s] ? b6[s] : cur;
                b6[s] = lo; cur = hi;
            }
        }
#pragma unroll
        for (int j = 0; j < 6; ++j) s_ek[sub][p][j] = b6[j];
    }
    __syncthreads();

    // P4a: 4-way merge -> exact top-16 ids
    if (t < 64) {
        int p0 = 0, p1 = 0, p2 = 0, p3 = 0;
#pragma unroll 1
        for (int k = 0; k < KNN; ++k) {
            unsigned long long k0 = (p0 < 6) ? s_ek[0][t][p0] : ~0ULL;
            unsigned long long k1 = (p1 < 6) ? s_ek[1][t][p1] : ~0ULL;
            unsigned long long k2 = (p2 < 6) ? s_ek[2][t][p2] : ~0ULL;
            unsigned long long k3 = (p3 < 6) ? s_ek[3][t][p3] : ~0ULL;
            unsigned long long bk = k0; int bq = 0;
            if (k1 < bk) { bk = k1; bq = 1; }
            if (k2 < bk) { bk = k2; bq = 2; }
            if (k3 < bk) { bk = k3; bq = 3; }
            s_out[t][k] = (int)(bk & 0xFFFu);
            if (bq == 0) ++p0; else if (bq == 1) ++p1; else if (bq == 2) ++p2; else ++p3;
        }
    }
    __syncthreads();

    // P4b: gather + max-pool
    {
        int pp = t >> 2;
        int cg = (t & 3) * 16;
        size_t gp2 = (size_t)b * NN + n0 + pp;
        float acc[16];
#pragma unroll
        for (int i = 0; i < 16; ++i) acc[i] = -3.4e38f;
#pragma unroll 1
        for (int k = 0; k < KNN; ++k) {
            int idx = s_out[pp][k];
            const float4* src = (const float4*)(xb + (size_t)idx * CIN + cg);
#pragma unroll
            for (int j2 = 0; j2 < 4; ++j2) {
                float4 v = src[j2];
                acc[4 * j2 + 0] = fmaxf(acc[4 * j2 + 0], v.x);
                acc[4 * j2 + 1] = fmaxf(acc[4 * j2 + 1], v.y);
                acc[4 * j2 + 2] = fmaxf(acc[4 * j2 + 2], v.z);
                acc[4 * j2 + 3] = fmaxf(acc[4 * j2 + 3], v.w);
            }
        }
        float4* dst = (float4*)(pooled + gp2 * CIN + cg);
#pragma unroll
        for (int j2 = 0; j2 < 4; ++j2)
            dst[j2] = make_float4(acc[4 * j2 + 0], acc[4 * j2 + 1],
                                  acc[4 * j2 + 2], acc[4 * j2 + 3]);
    }
}

// ---------------------------------------------------------------------------
// Kernel 4: per-tile partials of M = sum_r p p^T (64x64) and s = sum_r p.
// Output layout: Mpart[block][4160]  (4096 M entries + 64 s entries)
// ---------------------------------------------------------------------------
__global__ __launch_bounds__(256) void cov_part_kernel(
    const float* __restrict__ pooled, float* __restrict__ Mpart)
{
    __shared__ float sP[64 * 64];
    size_t r0 = (size_t)blockIdx.x * 64;
    int t = threadIdx.x;

    for (int j = t; j < 64 * CIN / 4; j += 256)
        ((float4*)sP)[j] = ((const float4*)(pooled + r0 * CIN))[j];
    __syncthreads();

    int i  = t & 63;
    int j0 = (t >> 6) * 16;
    float acc[16];
#pragma unroll
    for (int k = 0; k < 16; ++k) acc[k] = 0.f;
#pragma unroll 1
    for (int r = 0; r < 64; ++r) {
        float a = sP[r * 64 + i];
#pragma unroll
        for (int k4 = 0; k4 < 4; ++k4) {
            float4 bv = *(const float4*)&sP[r * 64 + j0 + 4 * k4];
            acc[4 * k4 + 0] = fmaf(bv.x, a, acc[4 * k4 + 0]);
            acc[4 * k4 + 1] = fmaf(bv.y, a, acc[4 * k4 + 1]);
            acc[4 * k4 + 2] = fmaf(bv.z, a, acc[4 * k4 + 2]);
            acc[4 * k4 + 3] = fmaf(bv.w, a, acc[4 * k4 + 3]);
        }
    }
    float* outb = Mpart + (size_t)blockIdx.x * 4160;
#pragma unroll
    for (int k = 0; k < 16; ++k) outb[(j0 + k) * 64 + i] = acc[k];
    if (t < 64) {
        float ssum = 0.f;
#pragma unroll 1
        for (int r = 0; r < 64; ++r) ssum += sP[r * 64 + t];
        outb[4096 + t] = ssum;
    }
}

// ---------------------------------------------------------------------------
// Kernel 5: reduce 512 partials -> Mred[4160]
// ---------------------------------------------------------------------------
__global__ __launch_bounds__(256) void reduce_kernel(
    const float* __restrict__ Mpart, float* __restrict__ Mred)
{
    int e = blockIdx.x * 256 + threadIdx.x;
    if (e < 4160) {
        float s = 0.f;
#pragma unroll 4
        for (int k = 0; k < 512; ++k) s += Mpart[(size_t)k * 4160 + e];
        Mred[e] = s;
    }
}

// ---------------------------------------------------------------------------
// Kernel 6: per-channel BN scale/shift from exact sums:
//   sum_y  = W_c.s + N b_c ;  sum_y2 = W_c M W_c^T + 2 b_c (W_c.s) + N b_c^2
//   S = gamma*rsqrt(var+eps);  T = beta + (b_c - mean)*S
// Single block, 2 threads per channel.
// ---------------------------------------------------------------------------
__global__ __launch_bounds__(256) void bn_prep_kernel(
    const float* __restrict__ Mred, const float* __restrict__ W,
    const float* __restrict__ bias, const float* __restrict__ gamma,
    const float* __restrict__ beta, float* __restrict__ ss)
{
    __shared__ float sM[64 * 64];
    __shared__ float ssv[64];
    __shared__ float sred[256];

    int t = threadIdx.x;
    for (int j = t; j < 1024; j += 256)
        ((float4*)sM)[j] = ((const float4*)Mred)[j];
    if (t < 64) ssv[t] = Mred[4096 + t];
    __syncthreads();

    int c  = t & 127;
    int hf = t >> 7;

    float wr[64];
    {
        const float4* wp = (const float4*)(W + (size_t)c * 64);
#pragma unroll
        for (int j = 0; j < 16; ++j) {
            float4 v = wp[j];
            wr[4 * j + 0] = v.x; wr[4 * j + 1] = v.y;
            wr[4 * j + 2] = v.z; wr[4 * j + 3] = v.w;
        }
    }

    float qf = 0.f;
#pragma unroll 1
    for (int jj = 0; jj < 32; ++jj) {
        int j = hf * 32 + jj;
        float wj = W[(size_t)c * 64 + j];
        float s4 = 0.f;
#pragma unroll
        for (int i4 = 0; i4 < 16; ++i4) {
            float4 mv = *(const float4*)&sM[j * 64 + 4 * i4];
            s4 = fmaf(wr[4 * i4 + 0], mv.x, s4);
            s4 = fmaf(wr[4 * i4 + 1], mv.y, s4);
            s4 = fmaf(wr[4 * i4 + 2], mv.z, s4);
            s4 = fmaf(wr[4 * i4 + 3], mv.w, s4);
        }
        qf = fmaf(wj, s4, qf);
    }
    sred[t] = qf;
    __syncthreads();
    if (hf == 0) {
        float q = sred[c] + sred[128 + c];
        float Ws = 0.f;
#pragma unroll
        for (int i = 0; i < 64; ++i) Ws = fmaf(wr[i], ssv[i], Ws);
        const float invN = 1.0f / (float)NTOT;
        float bc   = bias[c];
        float mean = Ws * invN + bc;
        float Ey2  = q * invN + 2.0f * bc * Ws * invN + bc * bc;
        float var  = Ey2 - mean * mean;
        float S    = gamma[c] * rsqrtf(var + 1e-5f);
        float T    = beta[c] + (bc - mean) * S;
        ss[c] = S;
        ss[COUT + c] = T;
    }
}

// ---------------------------------------------------------------------------
// Kernel 7: fused conv1x1 + BN + ReLU: out = max((W_c.p)*S_c + T_c, 0)
// ---------------------------------------------------------------------------
__global__ __launch_bounds__(256) void gemm_bn_out_kernel(
    const float* __restrict__ pooled, const float* __restrict__ W,
    const float* __restrict__ ss, float* __restrict__ out)
{
    __shared__ float sW[COUT * CIN];    // 32 KB
    __shared__ float sP[64 * CIN];      // 16 KB

    size_t r0 = (size_t)blockIdx.x * 64;
    int t = threadIdx.x;

    for (int j = t; j < COUT * CIN / 4; j += 256)
        ((float4*)sW)[j] = ((const float4*)W)[j];
    for (int j = t; j < 64 * CIN / 4; j += 256)
        ((float4*)sP)[j] = ((const float4*)(pooled + r0 * CIN))[j];
    __syncthreads();

    int c = t & 127;
    int h = t >> 7;
    float wr[CIN];
#pragma unroll
    for (int k = 0; k < CIN; ++k) wr[k] = sW[c * CIN + k];
    float Sc = ss[c];
    float Tc = ss[COUT + c];

#pragma unroll 1
    for (int i = 0; i < 32; ++i) {
        int r = h * 32 + i;             // wave-uniform -> LDS broadcast
        float a0 = 0.f, a1 = 0.f, a2 = 0.f, a3 = 0.f;
#pragma unroll
        for (int k = 0; k < CIN; k += 4) {
            a0 = fmaf(wr[k + 0], sP[r * CIN + k + 0], a0);
            a1 = fmaf(wr[k + 1], sP[r * CIN + k + 1], a1);
            a2 = fmaf(wr[k + 2], sP[r * CIN + k + 2], a2);
            a3 = fmaf(wr[k + 3], sP[r * CIN + k + 3], a3);
        }
        float v = (a0 + a1) + (a2 + a3);
        out[(r0 + r) * COUT + c] = fmaxf(fmaf(v, Sc, Tc), 0.0f);
    }
}

// ---------------------------------------------------------------------------
// ws layout (max 24.5 MiB concurrent; 25 MiB known-safe):
//   [0, 128K)            sq (fp32)
//   [256K, 4.25M)        xh (fp16, 4 MB)
//   [4.5M, 16.5M)        sub_k (u32, 32768 x 96 = 12 MB)  — consumed by rescue
//   [4.5M, 12.63M)       Mpart (8.13 MB)                  — aliases sub_k, after rescue
//   [13M, 13.02M)        Mred (4160 fp32)
//   [13.25M, +1K)        ss (scale[128], shift[128])
//   [16.5M, 24.5M)       pooled (fp32, 8 MB)
// ---------------------------------------------------------------------------
extern "C" void kernel_launch(void* const* d_in, const int* in_sizes, int n_in,
                              void* d_out, int out_size, void* d_ws, size_t ws_size,
                              hipStream_t stream)
{
    const float* x     = (const float*)d_in[0];
    const float* W     = (const float*)d_in[1];
    const float* bias  = (const float*)d_in[2];
    const float* gamma = (const float*)d_in[3];
    const float* beta  = (const float*)d_in[4];
    float* out = (float*)d_out;

    char* ws = (char*)d_ws;
    float*    sq     = (float*)(ws);
    _Float16* xh     = (_Float16*)(ws + 262144);
    unsigned* sub_k  = (unsigned*)(ws + 4718592);
    float*    Mpart  = (float*)(ws + 4718592);
    float*    Mred   = (float*)(ws + 13631488);
    float*    ss     = (float*)(ws + 13893632);
    float*    pooled = (float*)(ws + 17301504);

    hipLaunchKernelGGL(prep_kernel, dim3(NTOT / 256), dim3(256), 0, stream,
                       x, sq, xh);
    hipLaunchKernelGGL(knn_scan_mfma_kernel, dim3(NTOT / 64 * 2), dim3(256), 0, stream,
                       xh, sq, sub_k);
    hipLaunchKernelGGL(rescue_pool_kernel, dim3(NTOT / 64), dim3(256), 0, stream,
                       x, sq, sub_k, pooled);
    hipLaunchKernelGGL(cov_part_kernel, dim3(NTOT / 64), dim3(256), 0, stream,
                       pooled, Mpart);
    hipLaunchKernelGGL(reduce_kernel, dim3(17), dim3(256), 0, stream,
                       Mpart, Mred);
    hipLaunchKernelGGL(bn_prep_kernel, dim3(1), dim3(256), 0, stream,
                       Mred, W, bias, gamma, beta, ss);
    hipLaunchKernelGGL(gemm_bn_out_kernel, dim3(NTOT / 64), dim3(256), 0, stream,
                       pooled, W, ss, out);
}

// Round 7
// 253.742 us; speedup vs baseline: 1.2740x; 1.2740x over previous
//
#include <hip/hip_runtime.h>

#define BB   8
#define NN   4096
#define CIN  64
#define COUT 128
#define KNN  16
#define NTOT (BB * NN)

typedef _Float16 half8 __attribute__((ext_vector_type(8)));
typedef float f32x4 __attribute__((ext_vector_type(4)));

// bitonic sort 16 ascending, fully unrolled (all reg indices compile-time)
__device__ __forceinline__ void bitonic_sort16(unsigned a[16]) {
#pragma unroll
    for (int kk = 2; kk <= 16; kk <<= 1) {
#pragma unroll
        for (int jj = kk >> 1; jj > 0; jj >>= 1) {
#pragma unroll
            for (int i = 0; i < 16; ++i) {
                int l = i ^ jj;
                if (l > i) {
                    unsigned lo = a[i] < a[l] ? a[i] : a[l];
                    unsigned hi = a[i] < a[l] ? a[l] : a[i];
                    if ((i & kk) == 0) { a[i] = lo; a[l] = hi; }
                    else               { a[i] = hi; a[l] = lo; }
                }
            }
        }
    }
}

// ---------------------------------------------------------------------------
// Kernel 1: per-point sqnorm + fp32->fp16 x; block 0 also converts W to fp16
// and zeroes the BN stats accumulator.
// ---------------------------------------------------------------------------
__global__ __launch_bounds__(256) void prep_kernel(
    const float* __restrict__ x, const float* __restrict__ W,
    float* __restrict__ sq, _Float16* __restrict__ xh,
    _Float16* __restrict__ Wh, float* __restrict__ stats)
{
    int i = blockIdx.x * 256 + threadIdx.x;            // point id
    const float4* xr = (const float4*)(x + (size_t)i * CIN);
    half8* xw = (half8*)(xh + (size_t)i * CIN);
    float s0 = 0.f, s1 = 0.f;
#pragma unroll
    for (int j = 0; j < 8; ++j) {
        float4 a = xr[2 * j], b = xr[2 * j + 1];
        s0 = fmaf(a.x, a.x, s0); s0 = fmaf(a.y, a.y, s0);
        s0 = fmaf(a.z, a.z, s0); s0 = fmaf(a.w, a.w, s0);
        s1 = fmaf(b.x, b.x, s1); s1 = fmaf(b.y, b.y, s1);
        s1 = fmaf(b.z, b.z, s1); s1 = fmaf(b.w, b.w, s1);
        half8 h;
        h[0] = (_Float16)a.x; h[1] = (_Float16)a.y;
        h[2] = (_Float16)a.z; h[3] = (_Float16)a.w;
        h[4] = (_Float16)b.x; h[5] = (_Float16)b.y;
        h[6] = (_Float16)b.z; h[7] = (_Float16)b.w;
        xw[j] = h;
    }
    sq[i] = s0 + s1;

    if (blockIdx.x == 0) {
        int t = threadIdx.x;
        stats[t] = 0.0f;                               // sum[128], sumsq[128]
        const float4* wp4 = (const float4*)W;          // 2048 float4
        half8* wh8 = (half8*)Wh;                       // 1024 half8
#pragma unroll
        for (int j = 0; j < 4; ++j) {
            int idx = t * 4 + j;
            float4 a = wp4[2 * idx], b = wp4[2 * idx + 1];
            half8 h;
            h[0] = (_Float16)a.x; h[1] = (_Float16)a.y;
            h[2] = (_Float16)a.z; h[3] = (_Float16)a.w;
            h[4] = (_Float16)b.x; h[5] = (_Float16)b.y;
            h[6] = (_Float16)b.z; h[7] = (_Float16)b.w;
            wh8[idx] = h;
        }
    }
}

// ---------------------------------------------------------------------------
// Kernel 2: MFMA kNN scan (R6 structure: dbuf staging, bitonic selection),
// s_key back to stride 68 + uint4 reads (measured-better bank geometry).
// ---------------------------------------------------------------------------
__global__ __launch_bounds__(256) void knn_scan_mfma_kernel(
    const _Float16* __restrict__ xh, const float* __restrict__ sq,
    unsigned* __restrict__ sub_k)
{
    __shared__ _Float16 sBT[2][8][64][8];  // 16 KB dbuf [buf][k-granule][cand][8]
    __shared__ unsigned s_key[64 * 68];    // 17 KB [row][col] stride 68
    __shared__ float    s_sqm[2][64];

    int blk  = blockIdx.x;
    int tile = blk >> 1;
    int half = blk & 1;
    int b    = tile >> 6;
    int n0   = (tile & 63) * 64;
    int t    = threadIdx.x;
    int l    = t & 63;
    int w    = t >> 6;
    int quad = l >> 4;
    int c16  = l & 15;
    int p    = l;                          // selection point
    int q    = w;                          // selection col strip

    const _Float16* xhb = xh + (size_t)b * NN * CIN;
    const float*    sqb = sq + (size_t)b * NN;

    float sqn_r[4];
#pragma unroll
    for (int r = 0; r < 4; ++r)
        sqn_r[r] = sqb[n0 + 16 * w + 4 * quad + r];

    int row_a = n0 + 16 * w + c16;
    half8 afrag0 = *(const half8*)(xhb + (size_t)row_a * CIN + 0 * 32 + quad * 8);
    half8 afrag1 = *(const half8*)(xhb + (size_t)row_a * CIN + 1 * 32 + quad * 8);

    unsigned best[16];
#pragma unroll
    for (int j = 0; j < 16; ++j) best[j] = 0xFFFFFFFFu;

    {
        int cb0 = half * 2048;
#pragma unroll
        for (int r2 = 0; r2 < 2; ++r2) {
            int f = r2 * 256 + t;
            int cand = f >> 3, g = f & 7;
            *(half8*)&sBT[0][g][cand][0] =
                *(const half8*)(xhb + (size_t)(cb0 + cand) * CIN + g * 8);
        }
        if (t < 64) s_sqm[0][t] = sqb[cb0 + t];
    }

#pragma unroll 1
    for (int c = 0; c < 32; ++c) {
        int cur = c & 1;
        int cbase = half * 2048 + c * 64;
        __syncthreads();

        // prefetch chunk c+1 to regs (hidden behind MFMA)
        half8 st0, st1; float sqm_n = 0.f;
        int cand0 = t >> 3, g0 = t & 7;
        int cand1 = (256 + t) >> 3, g1 = t & 7;
        bool do_stage = (c < 31);
        if (do_stage) {
            int cb_n = cbase + 64;
            st0 = *(const half8*)(xhb + (size_t)(cb_n + cand0) * CIN + g0 * 8);
            st1 = *(const half8*)(xhb + (size_t)(cb_n + cand1) * CIN + g1 * 8);
            if (t < 64) sqm_n = sqb[cb_n + t];
        }

        f32x4 acc[4];
#pragma unroll
        for (int n = 0; n < 4; ++n) acc[n] = (f32x4){0.f, 0.f, 0.f, 0.f};
#pragma unroll
        for (int n = 0; n < 4; ++n) {
            half8 b0 = *(const half8*)&sBT[cur][0 * 4 + quad][16 * n + c16][0];
            half8 b1 = *(const half8*)&sBT[cur][1 * 4 + quad][16 * n + c16][0];
            acc[n] = __builtin_amdgcn_mfma_f32_16x16x32_f16(afrag0, b0, acc[n], 0, 0, 0);
            acc[n] = __builtin_amdgcn_mfma_f32_16x16x32_f16(afrag1, b1, acc[n], 0, 0, 0);
        }

        if (do_stage) {
            *(half8*)&sBT[cur ^ 1][g0][cand0][0] = st0;
            *(half8*)&sBT[cur ^ 1][g1][cand1][0] = st1;
            if (t < 64) s_sqm[cur ^ 1][t] = sqm_n;
        }

        // epilogue: dist = max(sqn + sqm - 2*dot, 0); pack (trunc|id)
#pragma unroll
        for (int n = 0; n < 4; ++n) {
            int col = 16 * n + c16;
            float sm = s_sqm[cur][col];
            unsigned id = (unsigned)(cbase + col);
#pragma unroll
            for (int r = 0; r < 4; ++r) {
                int row = 16 * w + 4 * quad + r;
                float d = fmaxf(sqn_r[r] + sm - 2.0f * acc[n][r], 0.0f);
                s_key[row * 68 + col] = (__float_as_uint(d) & 0xFFFFF000u) | id;
            }
        }
        __syncthreads();

        // selection: 4x uint4 key loads, bitonic sort-16, bitonic merge-16
        unsigned a16[16];
#pragma unroll
        for (int j = 0; j < 4; ++j) {
            uint4 v = *(const uint4*)&s_key[p * 68 + q * 16 + 4 * j];
            a16[4 * j + 0] = v.x; a16[4 * j + 1] = v.y;
            a16[4 * j + 2] = v.z; a16[4 * j + 3] = v.w;
        }
        bitonic_sort16(a16);
        unsigned m16[16];
#pragma unroll
        for (int i = 0; i < 16; ++i)
            m16[i] = best[i] < a16[15 - i] ? best[i] : a16[15 - i];
#pragma unroll
        for (int d = 8; d > 0; d >>= 1) {
#pragma unroll
            for (int i = 0; i < 16; ++i) {
                if ((i & d) == 0) {
                    unsigned xx = m16[i], yy = m16[i | d];
                    unsigned lo = xx < yy ? xx : yy;
                    unsigned hi = xx < yy ? yy : xx;
                    m16[i] = lo; m16[i | d] = hi;
                }
            }
        }
#pragma unroll
        for (int i = 0; i < 16; ++i) best[i] = m16[i];
    }

    // write lowest 12 keys: [point][half*4+q][12]
    size_t base = (((size_t)b * NN + n0 + p) * 8 + half * 4 + q) * 12;
    uint4* dst = (uint4*)(sub_k + base);
    dst[0] = make_uint4(best[0], best[1], best[2],  best[3]);
    dst[1] = make_uint4(best[4], best[5], best[6],  best[7]);
    dst[2] = make_uint4(best[8], best[9], best[10], best[11]);
}

// ---------------------------------------------------------------------------
// Kernel 3: rescue + gather + max-pool (R5-proven), now emitting fp16 pooled.
// ---------------------------------------------------------------------------
__global__ __launch_bounds__(256) void rescue_pool_kernel(
    const float* __restrict__ x, const float* __restrict__ sq,
    const unsigned* __restrict__ sub_k, _Float16* __restrict__ ph)
{
    __shared__ unsigned s_pk[4][64][17];
    __shared__ unsigned short s_cand[64][26];
    __shared__ unsigned long long s_ek[4][64][6];
    __shared__ int s_out[64][KNN];

    int blk = blockIdx.x;
    int b   = blk >> 6;
    int n0  = (blk & 63) * 64;
    int t   = threadIdx.x;
    int p   = t & 63;
    int sub = t >> 6;
    const float* xb  = x  + (size_t)b * NN * CIN;
    const float* sqb = sq + (size_t)b * NN;
    size_t gp = (size_t)b * NN + n0 + p;

    float xn[CIN];
    {
        const float4* xr = (const float4*)(xb + (size_t)(n0 + p) * CIN);
#pragma unroll
        for (int j = 0; j < CIN / 4; ++j) {
            float4 v = xr[j];
            xn[4 * j + 0] = v.x; xn[4 * j + 1] = v.y;
            xn[4 * j + 2] = v.z; xn[4 * j + 3] = v.w;
        }
    }
    float sqn = sqb[n0 + p];

    // P1: CE 24 approx keys -> sorted top-16
    {
        unsigned bk[16];
#pragma unroll
        for (int j = 0; j < 16; ++j) bk[j] = 0xFFFFFFFFu;
        const uint4* kp = (const uint4*)(sub_k + gp * 96 + sub * 24);
#pragma unroll
        for (int j = 0; j < 6; ++j) {
            uint4 kv = kp[j];
            unsigned kk[4] = { kv.x, kv.y, kv.z, kv.w };
#pragma unroll
            for (int e = 0; e < 4; ++e) {
                unsigned cur = kk[e];
#pragma unroll
                for (int s = 0; s < 16; ++s) {
                    unsigned lo = bk[s] < cur ? bk[s] : cur;
                    unsigned hi = bk[s] < cur ? cur : bk[s];
                    bk[s] = lo; cur = hi;
                }
            }
        }
#pragma unroll
        for (int j = 0; j < 16; ++j) s_pk[sub][p][j] = bk[j];
    }
    __syncthreads();

    // P2: 4-way merge -> top-24 ids
    if (t < 64) {
        int p0 = 0, p1 = 0, p2 = 0, p3 = 0;
#pragma unroll 1
        for (int k = 0; k < 24; ++k) {
            unsigned k0 = (p0 < 16) ? s_pk[0][t][p0] : 0xFFFFFFFFu;
            unsigned k1 = (p1 < 16) ? s_pk[1][t][p1] : 0xFFFFFFFFu;
            unsigned k2 = (p2 < 16) ? s_pk[2][t][p2] : 0xFFFFFFFFu;
            unsigned k3 = (p3 < 16) ? s_pk[3][t][p3] : 0xFFFFFFFFu;
            unsigned bk = k0; int bq = 0;
            if (k1 < bk) { bk = k1; bq = 1; }
            if (k2 < bk) { bk = k2; bq = 2; }
            if (k3 < bk) { bk = k3; bq = 3; }
            s_cand[t][k] = (unsigned short)(bk & 0xFFFu);
            if (bq == 0) ++p0; else if (bq == 1) ++p1; else if (bq == 2) ++p2; else ++p3;
        }
    }
    __syncthreads();

    // P3: exact fp32 distances for 6 ids/thread, reference-faithful 64-bit keys
    {
        unsigned long long b6[6];
#pragma unroll
        for (int j = 0; j < 6; ++j) b6[j] = ~0ULL;
#pragma unroll 1
        for (int j = 0; j < 6; ++j) {
            int m = s_cand[p][sub * 6 + j];
            const float4* xm4 = (const float4*)(xb + (size_t)m * CIN);
            float d0 = 0.f, d1 = 0.f, d2 = 0.f, d3 = 0.f;
#pragma unroll
            for (int cc = 0; cc < CIN / 4; ++cc) {
                float4 v = xm4[cc];
                d0 = fmaf(xn[4 * cc + 0], v.x, d0);
                d1 = fmaf(xn[4 * cc + 1], v.y, d1);
                d2 = fmaf(xn[4 * cc + 2], v.z, d2);
                d3 = fmaf(xn[4 * cc + 3], v.w, d3);
            }
            float d = sqn + sqb[m] - 2.0f * ((d0 + d1) + (d2 + d3));
            unsigned bbits = __float_as_uint(d);
            unsigned sgn   = (unsigned)((int)bbits >> 31);
            unsigned u     = bbits ^ (sgn | 0x80000000u);
            unsigned long long cur = ((unsigned long long)u << 32) | (unsigned)m;
#pragma unroll
            for (int s = 0; s < 6; ++s) {
                unsigned long long lo = cur < b6[s] ? cur : b6[s];
                unsigned long long hi = cur < b6[s] ? b6[s] : cur;
                b6[s] = lo; cur = hi;
            }
        }
#pragma unroll
        for (int j = 0; j < 6; ++j) s_ek[sub][p][j] = b6[j];
    }
    __syncthreads();

    // P4a: 4-way merge -> exact top-16 ids
    if (t < 64) {
        int p0 = 0, p1 = 0, p2 = 0, p3 = 0;
#pragma unroll 1
        for (int k = 0; k < KNN; ++k) {
            unsigned long long k0 = (p0 < 6) ? s_ek[0][t][p0] : ~0ULL;
            unsigned long long k1 = (p1 < 6) ? s_ek[1][t][p1] : ~0ULL;
            unsigned long long k2 = (p2 < 6) ? s_ek[2][t][p2] : ~0ULL;
            unsigned long long k3 = (p3 < 6) ? s_ek[3][t][p3] : ~0ULL;
            unsigned long long bk = k0; int bq = 0;
            if (k1 < bk) { bk = k1; bq = 1; }
            if (k2 < bk) { bk = k2; bq = 2; }
            if (k3 < bk) { bk = k3; bq = 3; }
            s_out[t][k] = (int)(bk & 0xFFFu);
            if (bq == 0) ++p0; else if (bq == 1) ++p1; else if (bq == 2) ++p2; else ++p3;
        }
    }
    __syncthreads();

    // P4b: gather + max-pool -> fp16 pooled
    {
        int pp = t >> 2;
        int cg = (t & 3) * 16;
        size_t gp2 = (size_t)b * NN + n0 + pp;
        float acc[16];
#pragma unroll
        for (int i = 0; i < 16; ++i) acc[i] = -3.4e38f;
#pragma unroll 1
        for (int k = 0; k < KNN; ++k) {
            int idx = s_out[pp][k];
            const float4* src = (const float4*)(xb + (size_t)idx * CIN + cg);
#pragma unroll
            for (int j2 = 0; j2 < 4; ++j2) {
                float4 v = src[j2];
                acc[4 * j2 + 0] = fmaxf(acc[4 * j2 + 0], v.x);
                acc[4 * j2 + 1] = fmaxf(acc[4 * j2 + 1], v.y);
                acc[4 * j2 + 2] = fmaxf(acc[4 * j2 + 2], v.z);
                acc[4 * j2 + 3] = fmaxf(acc[4 * j2 + 3], v.w);
            }
        }
        half8 h0, h1;
#pragma unroll
        for (int i = 0; i < 8; ++i) { h0[i] = (_Float16)acc[i]; h1[i] = (_Float16)acc[8 + i]; }
        half8* dst = (half8*)(ph + gp2 * CIN + cg);
        dst[0] = h0; dst[1] = h1;
    }
}

// ---------------------------------------------------------------------------
// Kernel 4: MFMA conv1x1 + bias; writes y (fp32) and per-channel sum/sumsq
// via LDS reduce + one atomic per channel per block. Block = 64 rows.
// A/B fragments loaded straight from global (L1/L2-hot), no staging.
// ---------------------------------------------------------------------------
__global__ __launch_bounds__(256) void gemm_mfma_stats_kernel(
    const _Float16* __restrict__ ph, const _Float16* __restrict__ Wh,
    const float* __restrict__ bias, float* __restrict__ y, float* __restrict__ stats)
{
    __shared__ float s_red[16][130][2];   // padded: quad stride 260 dw -> no conflicts
    __shared__ float s_bias[128];

    size_t r0 = (size_t)blockIdx.x * 64;
    int t = threadIdx.x;
    int w = t >> 6, l = t & 63, quad = l >> 4, c16 = l & 15;

    if (t < 128) s_bias[t] = bias[t];

    const _Float16* arow = ph + (r0 + 16 * w + c16) * CIN;
    half8 a0 = *(const half8*)(arow + quad * 8);
    half8 a1 = *(const half8*)(arow + 32 + quad * 8);

    f32x4 acc[8];
#pragma unroll
    for (int n = 0; n < 8; ++n) acc[n] = (f32x4){0.f, 0.f, 0.f, 0.f};
#pragma unroll
    for (int n = 0; n < 8; ++n) {
        const _Float16* wrow = Wh + (size_t)(16 * n + c16) * CIN;
        half8 b0 = *(const half8*)(wrow + quad * 8);
        half8 b1 = *(const half8*)(wrow + 32 + quad * 8);
        acc[n] = __builtin_amdgcn_mfma_f32_16x16x32_f16(a0, b0, acc[n], 0, 0, 0);
        acc[n] = __builtin_amdgcn_mfma_f32_16x16x32_f16(a1, b1, acc[n], 0, 0, 0);
    }
    __syncthreads();                      // s_bias ready

    int idx16 = w * 4 + quad;
#pragma unroll
    for (int n = 0; n < 8; ++n) {
        int col = 16 * n + c16;
        float bc = s_bias[col];
        float s = 0.f, s2 = 0.f;
#pragma unroll
        for (int r = 0; r < 4; ++r) {
            int row = 16 * w + quad * 4 + r;
            float v = acc[n][r] + bc;
            y[(r0 + row) * COUT + col] = v;
            s += v; s2 = fmaf(v, v, s2);
        }
        s_red[idx16][col][0] = s;
        s_red[idx16][col][1] = s2;
    }
    __syncthreads();

    if (t < 128) {
        float S = 0.f, S2 = 0.f;
#pragma unroll
        for (int i = 0; i < 16; ++i) { S += s_red[i][t][0]; S2 += s_red[i][t][1]; }
        atomicAdd(&stats[t], S);
        atomicAdd(&stats[COUT + t], S2);
    }
}

// ---------------------------------------------------------------------------
// Kernel 5: BatchNorm (population stats) + ReLU, float4 per thread
// ---------------------------------------------------------------------------
__global__ __launch_bounds__(256) void bn_relu_kernel(
    const float* __restrict__ y, const float* __restrict__ stats,
    const float* __restrict__ gamma, const float* __restrict__ beta,
    float* __restrict__ out)
{
    int i = blockIdx.x * 256 + threadIdx.x;            // float4 index
    float4 v = ((const float4*)y)[i];
    int c = (i * 4) & (COUT - 1);
    float r[4] = { v.x, v.y, v.z, v.w };
    float o[4];
    const float invM = 1.0f / (float)NTOT;
#pragma unroll
    for (int j = 0; j < 4; ++j) {
        int cc = c + j;
        float mean = stats[cc] * invM;
        float var  = stats[COUT + cc] * invM - mean * mean;
        float inv  = rsqrtf(var + 1e-5f);
        float val  = (r[j] - mean) * inv * gamma[cc] + beta[cc];
        o[j] = fmaxf(val, 0.0f);
    }
    ((float4*)out)[i] = make_float4(o[0], o[1], o[2], o[3]);
}

// ---------------------------------------------------------------------------
// ws layout (<= 20.5 MiB; 25 MiB known-safe):
//   [0, 128K)            sq (fp32)
//   [128K, 129K)         stats (sum[128], sumsq[128])
//   [160K, 176K)         Wh (fp16, 16 KB)
//   [256K, 4.25M)        xh (fp16, 4 MB)         — dead after scan
//   [4.5M, 16.5M)        sub_k (u32, 12 MB)      — dead after rescue
//   [256K, 16.25M)       y (fp32, 16 MB)         — aliases xh + sub_k
//   [16.5M, 20.5M)       ph (fp16 pooled, 4 MB)
// ---------------------------------------------------------------------------
extern "C" void kernel_launch(void* const* d_in, const int* in_sizes, int n_in,
                              void* d_out, int out_size, void* d_ws, size_t ws_size,
                              hipStream_t stream)
{
    const float* x     = (const float*)d_in[0];
    const float* W     = (const float*)d_in[1];
    const float* bias  = (const float*)d_in[2];
    const float* gamma = (const float*)d_in[3];
    const float* beta  = (const float*)d_in[4];
    float* out = (float*)d_out;

    char* ws = (char*)d_ws;
    float*     sq    = (float*)(ws);
    float*     stats = (float*)(ws + 131072);
    _Float16*  Wh    = (_Float16*)(ws + 163840);
    _Float16*  xh    = (_Float16*)(ws + 262144);
    unsigned*  sub_k = (unsigned*)(ws + 4718592);
    float*     y     = (float*)(ws + 262144);
    _Float16*  ph    = (_Float16*)(ws + 17301504);

    hipLaunchKernelGGL(prep_kernel, dim3(NTOT / 256), dim3(256), 0, stream,
                       x, W, sq, xh, Wh, stats);
    hipLaunchKernelGGL(knn_scan_mfma_kernel, dim3(NTOT / 64 * 2), dim3(256), 0, stream,
                       xh, sq, sub_k);
    hipLaunchKernelGGL(rescue_pool_kernel, dim3(NTOT / 64), dim3(256), 0, stream,
                       x, sq, sub_k, ph);
    hipLaunchKernelGGL(gemm_mfma_stats_kernel, dim3(NTOT / 64), dim3(256), 0, stream,
                       ph, Wh, bias, y, stats);
    hipLaunchKernelGGL(bn_relu_kernel, dim3(NTOT * COUT / (4 * 256)), dim3(256), 0, stream,
                       y, stats, gamma, beta, out);
}

// Round 8
// 248.602 us; speedup vs baseline: 1.3003x; 1.0207x over previous
//
#include <hip/hip_runtime.h>

#define BB   8
#define NN   4096
#define CIN  64
#define COUT 128
#define KNN  16
#define NTOT (BB * NN)

typedef _Float16 half8 __attribute__((ext_vector_type(8)));
typedef float f32x4 __attribute__((ext_vector_type(4)));

__device__ __forceinline__ void ce_u32(unsigned &x, unsigned &y) {
    unsigned lo = x < y ? x : y;
    unsigned hi = x < y ? y : x;
    x = lo; y = hi;
}

// Batcher odd-even mergesort, n=16: 63 CE (formula verified on n=4 -> the
// canonical 5-CE network). All indices compile-time after unrolling.
__device__ __forceinline__ void batcher_sort16(unsigned a[16]) {
#pragma unroll
    for (int p = 1; p < 16; p <<= 1) {
#pragma unroll
        for (int k = p; k >= 1; k >>= 1) {
#pragma unroll
            for (int j = k & (p - 1); j + k < 16; j += 2 * k) {
#pragma unroll
                for (int i = 0; i < k; ++i) {
                    if (i + j + k < 16 &&
                        (i + j) / (2 * p) == (i + j + k) / (2 * p))
                        ce_u32(a[i + j], a[i + j + k]);
                }
            }
        }
    }
}

// ---------------------------------------------------------------------------
// Kernel 1: per-point sqnorm + fp32->fp16 x (xh) + fp16 of -2x (xh2, exact
// power-of-2 scale so keys match the unscaled formulation bit-for-bit at the
// product level). Block 0 converts W to fp16 and zeroes BN stats.
// ---------------------------------------------------------------------------
__global__ __launch_bounds__(256) void prep_kernel(
    const float* __restrict__ x, const float* __restrict__ W,
    float* __restrict__ sq, _Float16* __restrict__ xh,
    _Float16* __restrict__ xh2, _Float16* __restrict__ Wh,
    float* __restrict__ stats)
{
    int i = blockIdx.x * 256 + threadIdx.x;            // point id
    const float4* xr = (const float4*)(x + (size_t)i * CIN);
    half8* xw  = (half8*)(xh  + (size_t)i * CIN);
    half8* xw2 = (half8*)(xh2 + (size_t)i * CIN);
    float s0 = 0.f, s1 = 0.f;
#pragma unroll
    for (int j = 0; j < 8; ++j) {
        float4 a = xr[2 * j], b = xr[2 * j + 1];
        s0 = fmaf(a.x, a.x, s0); s0 = fmaf(a.y, a.y, s0);
        s0 = fmaf(a.z, a.z, s0); s0 = fmaf(a.w, a.w, s0);
        s1 = fmaf(b.x, b.x, s1); s1 = fmaf(b.y, b.y, s1);
        s1 = fmaf(b.z, b.z, s1); s1 = fmaf(b.w, b.w, s1);
        half8 h, h2;
        h[0] = (_Float16)a.x; h[1] = (_Float16)a.y;
        h[2] = (_Float16)a.z; h[3] = (_Float16)a.w;
        h[4] = (_Float16)b.x; h[5] = (_Float16)b.y;
        h[6] = (_Float16)b.z; h[7] = (_Float16)b.w;
#pragma unroll
        for (int e = 0; e < 8; ++e) h2[e] = (_Float16)(-2.0f) * h[e];
        xw[j] = h; xw2[j] = h2;
    }
    sq[i] = s0 + s1;

    if (blockIdx.x == 0) {
        int t = threadIdx.x;
        stats[t] = 0.0f;                               // sum[128], sumsq[128]
        const float4* wp4 = (const float4*)W;
        half8* wh8 = (half8*)Wh;
#pragma unroll
        for (int j = 0; j < 4; ++j) {
            int idx = t * 4 + j;
            float4 a = wp4[2 * idx], b = wp4[2 * idx + 1];
            half8 h;
            h[0] = (_Float16)a.x; h[1] = (_Float16)a.y;
            h[2] = (_Float16)a.z; h[3] = (_Float16)a.w;
            h[4] = (_Float16)b.x; h[5] = (_Float16)b.y;
            h[6] = (_Float16)b.z; h[7] = (_Float16)b.w;
            wh8[idx] = h;
        }
    }
}

// ---------------------------------------------------------------------------
// Kernel 2: MFMA kNN scan. A operand = -2x (xh2), C pre-initialized with
// sqn+sqm so MFMA emits distances directly. Batcher-63 sort + bitonic merge
// selection. Writes lowest 12 keys per (point, half, strip).
// ---------------------------------------------------------------------------
__global__ __launch_bounds__(256) void knn_scan_mfma_kernel(
    const _Float16* __restrict__ xh, const _Float16* __restrict__ xh2,
    const float* __restrict__ sq, unsigned* __restrict__ sub_k)
{
    __shared__ _Float16 sBT[2][8][64][8];  // 16 KB dbuf [buf][k-granule][cand][8]
    __shared__ unsigned s_key[64 * 68];    // 17 KB [row][col] stride 68
    __shared__ float    s_sqm[2][64];

    int blk  = blockIdx.x;
    int tile = blk >> 1;
    int half = blk & 1;
    int b    = tile >> 6;
    int n0   = (tile & 63) * 64;
    int t    = threadIdx.x;
    int l    = t & 63;
    int w    = t >> 6;
    int quad = l >> 4;
    int c16  = l & 15;
    int p    = l;                          // selection point
    int q    = w;                          // selection col strip

    const _Float16* xhb  = xh  + (size_t)b * NN * CIN;
    const _Float16* xh2b = xh2 + (size_t)b * NN * CIN;
    const float*    sqb  = sq + (size_t)b * NN;

    float sqn_r[4];
#pragma unroll
    for (int r = 0; r < 4; ++r)
        sqn_r[r] = sqb[n0 + 16 * w + 4 * quad + r];

    int row_a = n0 + 16 * w + c16;
    half8 afrag0 = *(const half8*)(xh2b + (size_t)row_a * CIN + 0 * 32 + quad * 8);
    half8 afrag1 = *(const half8*)(xh2b + (size_t)row_a * CIN + 1 * 32 + quad * 8);

    unsigned best[16];
#pragma unroll
    for (int j = 0; j < 16; ++j) best[j] = 0xFFFFFFFFu;

    {
        int cb0 = half * 2048;
#pragma unroll
        for (int r2 = 0; r2 < 2; ++r2) {
            int f = r2 * 256 + t;
            int cand = f >> 3, g = f & 7;
            *(half8*)&sBT[0][g][cand][0] =
                *(const half8*)(xhb + (size_t)(cb0 + cand) * CIN + g * 8);
        }
        if (t < 64) s_sqm[0][t] = sqb[cb0 + t];
    }

#pragma unroll 1
    for (int c = 0; c < 32; ++c) {
        int cur = c & 1;
        int cbase = half * 2048 + c * 64;
        __syncthreads();

        // prefetch chunk c+1 to regs (hidden behind MFMA)
        half8 st0, st1; float sqm_n = 0.f;
        int cand0 = t >> 3, g0 = t & 7;
        int cand1 = (256 + t) >> 3, g1 = t & 7;
        bool do_stage = (c < 31);
        if (do_stage) {
            int cb_n = cbase + 64;
            st0 = *(const half8*)(xhb + (size_t)(cb_n + cand0) * CIN + g0 * 8);
            st1 = *(const half8*)(xhb + (size_t)(cb_n + cand1) * CIN + g1 * 8);
            if (t < 64) sqm_n = sqb[cb_n + t];
        }

        // MFMA with C = sqn+sqm: acc comes out as the distance directly
        f32x4 acc[4];
#pragma unroll
        for (int n = 0; n < 4; ++n) {
            float sm = s_sqm[cur][16 * n + c16];
            f32x4 ci;
            ci[0] = sqn_r[0] + sm; ci[1] = sqn_r[1] + sm;
            ci[2] = sqn_r[2] + sm; ci[3] = sqn_r[3] + sm;
            half8 b0 = *(const half8*)&sBT[cur][0 * 4 + quad][16 * n + c16][0];
            half8 b1 = *(const half8*)&sBT[cur][1 * 4 + quad][16 * n + c16][0];
            ci = __builtin_amdgcn_mfma_f32_16x16x32_f16(afrag0, b0, ci, 0, 0, 0);
            ci = __builtin_amdgcn_mfma_f32_16x16x32_f16(afrag1, b1, ci, 0, 0, 0);
            acc[n] = ci;
        }

        if (do_stage) {
            *(half8*)&sBT[cur ^ 1][g0][cand0][0] = st0;
            *(half8*)&sBT[cur ^ 1][g1][cand1][0] = st1;
            if (t < 64) s_sqm[cur ^ 1][t] = sqm_n;
        }

        // epilogue: clamp, pack (trunc-dist | id), write [row][col]
#pragma unroll
        for (int n = 0; n < 4; ++n) {
            int col = 16 * n + c16;
            unsigned id = (unsigned)(cbase + col);
#pragma unroll
            for (int r = 0; r < 4; ++r) {
                int row = 16 * w + 4 * quad + r;
                float d = fmaxf(acc[n][r], 0.0f);
                s_key[row * 68 + col] = (__float_as_uint(d) & 0xFFFFF000u) | id;
            }
        }
        __syncthreads();

        // selection: 4x uint4 key loads, Batcher sort-16, bitonic merge-16
        unsigned a16[16];
#pragma unroll
        for (int j = 0; j < 4; ++j) {
            uint4 v = *(const uint4*)&s_key[p * 68 + q * 16 + 4 * j];
            a16[4 * j + 0] = v.x; a16[4 * j + 1] = v.y;
            a16[4 * j + 2] = v.z; a16[4 * j + 3] = v.w;
        }
        batcher_sort16(a16);
        unsigned m16[16];
#pragma unroll
        for (int i = 0; i < 16; ++i)
            m16[i] = best[i] < a16[15 - i] ? best[i] : a16[15 - i];
#pragma unroll
        for (int d = 8; d > 0; d >>= 1) {
#pragma unroll
            for (int i = 0; i < 16; ++i) {
                if ((i & d) == 0) ce_u32(m16[i], m16[i | d]);
            }
        }
#pragma unroll
        for (int i = 0; i < 16; ++i) best[i] = m16[i];
    }

    // write lowest 12 keys: [point][half*4+q][12]
    size_t base = (((size_t)b * NN + n0 + p) * 8 + half * 4 + q) * 12;
    uint4* dst = (uint4*)(sub_k + base);
    dst[0] = make_uint4(best[0], best[1], best[2],  best[3]);
    dst[1] = make_uint4(best[4], best[5], best[6],  best[7]);
    dst[2] = make_uint4(best[8], best[9], best[10], best[11]);
}

// ---------------------------------------------------------------------------
// Kernel 3: rescue + gather + max-pool. P1 is now a bitonic merge of the two
// already-sorted 12-streams (identical output to the old CE chain, ~10x fewer
// instrs). P4b gathers fp16 rows (max commutes with monotone rounding ->
// pooled bits identical to fp16(max of fp32)).
// ---------------------------------------------------------------------------
__global__ __launch_bounds__(256) void rescue_pool_kernel(
    const float* __restrict__ x, const _Float16* __restrict__ xh,
    const float* __restrict__ sq, const unsigned* __restrict__ sub_k,
    _Float16* __restrict__ ph)
{
    __shared__ unsigned s_pk[4][64][17];
    __shared__ unsigned short s_cand[64][26];
    __shared__ unsigned long long s_ek[4][64][6];
    __shared__ int s_out[64][KNN];

    int blk = blockIdx.x;
    int b   = blk >> 6;
    int n0  = (blk & 63) * 64;
    int t   = threadIdx.x;
    int p   = t & 63;
    int sub = t >> 6;
    const float*    xb  = x  + (size_t)b * NN * CIN;
    const _Float16* xhb = xh + (size_t)b * NN * CIN;
    const float*    sqb = sq + (size_t)b * NN;
    size_t gp = (size_t)b * NN + n0 + p;

    float xn[CIN];
    {
        const float4* xr = (const float4*)(xb + (size_t)(n0 + p) * CIN);
#pragma unroll
        for (int j = 0; j < CIN / 4; ++j) {
            float4 v = xr[j];
            xn[4 * j + 0] = v.x; xn[4 * j + 1] = v.y;
            xn[4 * j + 2] = v.z; xn[4 * j + 3] = v.w;
        }
    }
    float sqn = sqb[n0 + p];

    // P1: bitonic merge of two sorted-12 streams -> sorted lowest-16 of 24
    {
        const uint4* kp = (const uint4*)(sub_k + gp * 96 + sub * 24);
        uint4 v0 = kp[0], v1 = kp[1], v2 = kp[2];
        uint4 v3 = kp[3], v4 = kp[4], v5 = kp[5];
        unsigned A[16] = { v0.x, v0.y, v0.z, v0.w, v1.x, v1.y, v1.z, v1.w,
                           v2.x, v2.y, v2.z, v2.w,
                           0xFFFFFFFFu, 0xFFFFFFFFu, 0xFFFFFFFFu, 0xFFFFFFFFu };
        unsigned B[16] = { v3.x, v3.y, v3.z, v3.w, v4.x, v4.y, v4.z, v4.w,
                           v5.x, v5.y, v5.z, v5.w,
                           0xFFFFFFFFu, 0xFFFFFFFFu, 0xFFFFFFFFu, 0xFFFFFFFFu };
        unsigned m[16];
#pragma unroll
        for (int i = 0; i < 16; ++i) m[i] = A[i] < B[15 - i] ? A[i] : B[15 - i];
#pragma unroll
        for (int d = 8; d > 0; d >>= 1) {
#pragma unroll
            for (int i = 0; i < 16; ++i) {
                if ((i & d) == 0) ce_u32(m[i], m[i | d]);
            }
        }
#pragma unroll
        for (int j = 0; j < 16; ++j) s_pk[sub][p][j] = m[j];
    }
    __syncthreads();

    // P2: 4-way merge -> top-24 ids
    if (t < 64) {
        int p0 = 0, p1 = 0, p2 = 0, p3 = 0;
#pragma unroll 1
        for (int k = 0; k < 24; ++k) {
            unsigned k0 = (p0 < 16) ? s_pk[0][t][p0] : 0xFFFFFFFFu;
            unsigned k1 = (p1 < 16) ? s_pk[1][t][p1] : 0xFFFFFFFFu;
            unsigned k2 = (p2 < 16) ? s_pk[2][t][p2] : 0xFFFFFFFFu;
            unsigned k3 = (p3 < 16) ? s_pk[3][t][p3] : 0xFFFFFFFFu;
            unsigned bk = k0; int bq = 0;
            if (k1 < bk) { bk = k1; bq = 1; }
            if (k2 < bk) { bk = k2; bq = 2; }
            if (k3 < bk) { bk = k3; bq = 3; }
            s_cand[t][k] = (unsigned short)(bk & 0xFFFu);
            if (bq == 0) ++p0; else if (bq == 1) ++p1; else if (bq == 2) ++p2; else ++p3;
        }
    }
    __syncthreads();

    // P3: exact fp32 distances for 6 ids/thread, reference-faithful 64-bit keys
    {
        unsigned long long b6[6];
#pragma unroll
        for (int j = 0; j < 6; ++j) b6[j] = ~0ULL;
#pragma unroll 1
        for (int j = 0; j < 6; ++j) {
            int m = s_cand[p][sub * 6 + j];
            const float4* xm4 = (const float4*)(xb + (size_t)m * CIN);
            float d0 = 0.f, d1 = 0.f, d2 = 0.f, d3 = 0.f;
#pragma unroll
            for (int cc = 0; cc < CIN / 4; ++cc) {
                float4 v = xm4[cc];
                d0 = fmaf(xn[4 * cc + 0], v.x, d0);
                d1 = fmaf(xn[4 * cc + 1], v.y, d1);
                d2 = fmaf(xn[4 * cc + 2], v.z, d2);
                d3 = fmaf(xn[4 * cc + 3], v.w, d3);
            }
            float d = sqn + sqb[m] - 2.0f * ((d0 + d1) + (d2 + d3));
            unsigned bbits = __float_as_uint(d);
            unsigned sgn   = (unsigned)((int)bbits >> 31);
            unsigned u     = bbits ^ (sgn | 0x80000000u);
            unsigned long long cur = ((unsigned long long)u << 32) | (unsigned)m;
#pragma unroll
            for (int s = 0; s < 6; ++s) {
                unsigned long long lo = cur < b6[s] ? cur : b6[s];
                unsigned long long hi = cur < b6[s] ? b6[s] : cur;
                b6[s] = lo; cur = hi;
            }
        }
#pragma unroll
        for (int j = 0; j < 6; ++j) s_ek[sub][p][j] = b6[j];
    }
    __syncthreads();

    // P4a: 4-way merge -> exact top-16 ids
    if (t < 64) {
        int p0 = 0, p1 = 0, p2 = 0, p3 = 0;
#pragma unroll 1
        for (int k = 0; k < KNN; ++k) {
            unsigned long long k0 = (p0 < 6) ? s_ek[0][t][p0] : ~0ULL;
            unsigned long long k1 = (p1 < 6) ? s_ek[1][t][p1] : ~0ULL;
            unsigned long long k2 = (p2 < 6) ? s_ek[2][t][p2] : ~0ULL;
            unsigned long long k3 = (p3 < 6) ? s_ek[3][t][p3] : ~0ULL;
            unsigned long long bk = k0; int bq = 0;
            if (k1 < bk) { bk = k1; bq = 1; }
            if (k2 < bk) { bk = k2; bq = 2; }
            if (k3 < bk) { bk = k3; bq = 3; }
            s_out[t][k] = (int)(bk & 0xFFFu);
            if (bq == 0) ++p0; else if (bq == 1) ++p1; else if (bq == 2) ++p2; else ++p3;
        }
    }
    __syncthreads();

    // P4b: gather fp16 rows + max-pool (fp16 max == fp16 of fp32 max)
    {
        int pp = t >> 2;
        int cg = (t & 3) * 16;
        size_t gp2 = (size_t)b * NN + n0 + pp;
        const half8* r0p = (const half8*)(xhb + (size_t)s_out[pp][0] * CIN + cg);
        half8 m0 = r0p[0], m1 = r0p[1];
#pragma unroll 1
        for (int k = 1; k < KNN; ++k) {
            const half8* src = (const half8*)(xhb + (size_t)s_out[pp][k] * CIN + cg);
            half8 v0 = src[0], v1 = src[1];
#pragma unroll
            for (int e = 0; e < 8; ++e) {
                m0[e] = v0[e] > m0[e] ? v0[e] : m0[e];
                m1[e] = v1[e] > m1[e] ? v1[e] : m1[e];
            }
        }
        half8* dst = (half8*)(ph + gp2 * CIN + cg);
        dst[0] = m0; dst[1] = m1;
    }
}

// ---------------------------------------------------------------------------
// Kernel 4 (pass 1): MFMA conv1x1 + bias -> stats only (y never stored).
// ---------------------------------------------------------------------------
__global__ __launch_bounds__(256) void gemm_stats_kernel(
    const _Float16* __restrict__ ph, const _Float16* __restrict__ Wh,
    const float* __restrict__ bias, float* __restrict__ stats)
{
    __shared__ float s_red[16][130][2];
    __shared__ float s_bias[128];

    size_t r0 = (size_t)blockIdx.x * 64;
    int t = threadIdx.x;
    int w = t >> 6, l = t & 63, quad = l >> 4, c16 = l & 15;

    if (t < 128) s_bias[t] = bias[t];

    const _Float16* arow = ph + (r0 + 16 * w + c16) * CIN;
    half8 a0 = *(const half8*)(arow + quad * 8);
    half8 a1 = *(const half8*)(arow + 32 + quad * 8);

    f32x4 acc[8];
#pragma unroll
    for (int n = 0; n < 8; ++n) acc[n] = (f32x4){0.f, 0.f, 0.f, 0.f};
#pragma unroll
    for (int n = 0; n < 8; ++n) {
        const _Float16* wrow = Wh + (size_t)(16 * n + c16) * CIN;
        half8 b0 = *(const half8*)(wrow + quad * 8);
        half8 b1 = *(const half8*)(wrow + 32 + quad * 8);
        acc[n] = __builtin_amdgcn_mfma_f32_16x16x32_f16(a0, b0, acc[n], 0, 0, 0);
        acc[n] = __builtin_amdgcn_mfma_f32_16x16x32_f16(a1, b1, acc[n], 0, 0, 0);
    }
    __syncthreads();

    int idx16 = w * 4 + quad;
#pragma unroll
    for (int n = 0; n < 8; ++n) {
        int col = 16 * n + c16;
        float bc = s_bias[col];
        float s = 0.f, s2 = 0.f;
#pragma unroll
        for (int r = 0; r < 4; ++r) {
            float v = acc[n][r] + bc;
            s += v; s2 = fmaf(v, v, s2);
        }
        s_red[idx16][col][0] = s;
        s_red[idx16][col][1] = s2;
    }
    __syncthreads();

    if (t < 128) {
        float S = 0.f, S2 = 0.f;
#pragma unroll
        for (int i = 0; i < 16; ++i) { S += s_red[i][t][0]; S2 += s_red[i][t][1]; }
        atomicAdd(&stats[t], S);
        atomicAdd(&stats[COUT + t], S2);
    }
}

// ---------------------------------------------------------------------------
// Kernel 5 (pass 2): recompute identical MFMA y, fuse BN + ReLU -> out.
// out = max(dot*S + T, 0), S = gamma*rsqrt(var+eps), T = beta + (b-mean)*S.
// ---------------------------------------------------------------------------
__global__ __launch_bounds__(256) void gemm_bn_out_kernel(
    const _Float16* __restrict__ ph, const _Float16* __restrict__ Wh,
    const float* __restrict__ stats, const float* __restrict__ bias,
    const float* __restrict__ gamma, const float* __restrict__ beta,
    float* __restrict__ out)
{
    __shared__ float sS[128];
    __shared__ float sT[128];

    size_t r0 = (size_t)blockIdx.x * 64;
    int t = threadIdx.x;
    int w = t >> 6, l = t & 63, quad = l >> 4, c16 = l & 15;

    if (t < 128) {
        const float invN = 1.0f / (float)NTOT;
        float mean = stats[t] * invN;
        float var  = stats[COUT + t] * invN - mean * mean;
        float S    = gamma[t] * rsqrtf(var + 1e-5f);
        sS[t] = S;
        sT[t] = beta[t] + (bias[t] - mean) * S;
    }

    const _Float16* arow = ph + (r0 + 16 * w + c16) * CIN;
    half8 a0 = *(const half8*)(arow + quad * 8);
    half8 a1 = *(const half8*)(arow + 32 + quad * 8);

    f32x4 acc[8];
#pragma unroll
    for (int n = 0; n < 8; ++n) acc[n] = (f32x4){0.f, 0.f, 0.f, 0.f};
#pragma unroll
    for (int n = 0; n < 8; ++n) {
        const _Float16* wrow = Wh + (size_t)(16 * n + c16) * CIN;
        half8 b0 = *(const half8*)(wrow + quad * 8);
        half8 b1 = *(const half8*)(wrow + 32 + quad * 8);
        acc[n] = __builtin_amdgcn_mfma_f32_16x16x32_f16(a0, b0, acc[n], 0, 0, 0);
        acc[n] = __builtin_amdgcn_mfma_f32_16x16x32_f16(a1, b1, acc[n], 0, 0, 0);
    }
    __syncthreads();

#pragma unroll
    for (int n = 0; n < 8; ++n) {
        int col = 16 * n + c16;
        float Sc = sS[col], Tc = sT[col];
#pragma unroll
        for (int r = 0; r < 4; ++r) {
            int row = 16 * w + quad * 4 + r;
            out[(r0 + row) * COUT + col] = fmaxf(fmaf(acc[n][r], Sc, Tc), 0.0f);
        }
    }
}

// ---------------------------------------------------------------------------
// ws layout (24.25 MiB max; 25 MiB known-safe). No y buffer at all.
//   [0, 128K)              sq (fp32)
//   [128K, 129K)           stats (sum[128], sumsq[128])
//   [160K, 176K)           Wh (fp16)
//   [256K, 4.25M)          xh  (fp16 x, 4 MB)
//   [4.25M, 8.25M)         xh2 (fp16 -2x, 4 MB)
//   [8.25M, 20.25M)        sub_k (u32, 32768 x 96 = 12 MB)
//   [20.25M, 24.25M)       ph (fp16 pooled, 4 MB)
// ---------------------------------------------------------------------------
extern "C" void kernel_launch(void* const* d_in, const int* in_sizes, int n_in,
                              void* d_out, int out_size, void* d_ws, size_t ws_size,
                              hipStream_t stream)
{
    const float* x     = (const float*)d_in[0];
    const float* W     = (const float*)d_in[1];
    const float* bias  = (const float*)d_in[2];
    const float* gamma = (const float*)d_in[3];
    const float* beta  = (const float*)d_in[4];
    float* out = (float*)d_out;

    char* ws = (char*)d_ws;
    float*     sq    = (float*)(ws);
    float*     stats = (float*)(ws + 131072);
    _Float16*  Wh    = (_Float16*)(ws + 163840);
    _Float16*  xh    = (_Float16*)(ws + 262144);
    _Float16*  xh2   = (_Float16*)(ws + 262144 + 4u * 1024 * 1024);
    unsigned*  sub_k = (unsigned*)(ws + 262144 + 8u * 1024 * 1024);
    _Float16*  ph    = (_Float16*)(ws + 262144 + 20u * 1024 * 1024);

    hipLaunchKernelGGL(prep_kernel, dim3(NTOT / 256), dim3(256), 0, stream,
                       x, W, sq, xh, xh2, Wh, stats);
    hipLaunchKernelGGL(knn_scan_mfma_kernel, dim3(NTOT / 64 * 2), dim3(256), 0, stream,
                       xh, xh2, sq, sub_k);
    hipLaunchKernelGGL(rescue_pool_kernel, dim3(NTOT / 64), dim3(256), 0, stream,
                       x, xh, sq, sub_k, ph);
    hipLaunchKernelGGL(gemm_stats_kernel, dim3(NTOT / 64), dim3(256), 0, stream,
                       ph, Wh, bias, stats);
    hipLaunchKernelGGL(gemm_bn_out_kernel, dim3(NTOT / 64), dim3(256), 0, stream,
                       ph, Wh, stats, bias, gamma, beta, out);
}

// Round 10
// 236.398 us; speedup vs baseline: 1.3674x; 1.0516x over previous
//
#include <hip/hip_runtime.h>

#define BB   8
#define NN   4096
#define CIN  64
#define COUT 128
#define KNN  16
#define NTOT (BB * NN)

typedef _Float16 half8 __attribute__((ext_vector_type(8)));
typedef float f32x4 __attribute__((ext_vector_type(4)));

__device__ __forceinline__ void ce_u32(unsigned &x, unsigned &y) {
    unsigned lo = x < y ? x : y;
    unsigned hi = x < y ? y : x;
    x = lo; y = hi;
}

// Batcher odd-even mergesort, n=16: 63 CE. All indices compile-time.
__device__ __forceinline__ void batcher_sort16(unsigned a[16]) {
#pragma unroll
    for (int p = 1; p < 16; p <<= 1) {
#pragma unroll
        for (int k = p; k >= 1; k >>= 1) {
#pragma unroll
            for (int j = k & (p - 1); j + k < 16; j += 2 * k) {
#pragma unroll
                for (int i = 0; i < k; ++i) {
                    if (i + j + k < 16 &&
                        (i + j) / (2 * p) == (i + j + k) / (2 * p))
                        ce_u32(a[i + j], a[i + j + k]);
                }
            }
        }
    }
}

// ---------------------------------------------------------------------------
// Kernel 1: per-point sqnorm + fp16 x (xh) + fp16 -2x (xh2). Block 0 converts
// W to fp16 and zeroes BN stats. (R8-proven)
// ---------------------------------------------------------------------------
__global__ __launch_bounds__(256) void prep_kernel(
    const float* __restrict__ x, const float* __restrict__ W,
    float* __restrict__ sq, _Float16* __restrict__ xh,
    _Float16* __restrict__ xh2, _Float16* __restrict__ Wh,
    float* __restrict__ stats)
{
    int i = blockIdx.x * 256 + threadIdx.x;            // point id
    const float4* xr = (const float4*)(x + (size_t)i * CIN);
    half8* xw  = (half8*)(xh  + (size_t)i * CIN);
    half8* xw2 = (half8*)(xh2 + (size_t)i * CIN);
    float s0 = 0.f, s1 = 0.f;
#pragma unroll
    for (int j = 0; j < 8; ++j) {
        float4 a = xr[2 * j], b = xr[2 * j + 1];
        s0 = fmaf(a.x, a.x, s0); s0 = fmaf(a.y, a.y, s0);
        s0 = fmaf(a.z, a.z, s0); s0 = fmaf(a.w, a.w, s0);
        s1 = fmaf(b.x, b.x, s1); s1 = fmaf(b.y, b.y, s1);
        s1 = fmaf(b.z, b.z, s1); s1 = fmaf(b.w, b.w, s1);
        half8 h, h2;
        h[0] = (_Float16)a.x; h[1] = (_Float16)a.y;
        h[2] = (_Float16)a.z; h[3] = (_Float16)a.w;
        h[4] = (_Float16)b.x; h[5] = (_Float16)b.y;
        h[6] = (_Float16)b.z; h[7] = (_Float16)b.w;
#pragma unroll
        for (int e = 0; e < 8; ++e) h2[e] = (_Float16)(-2.0f) * h[e];
        xw[j] = h; xw2[j] = h2;
    }
    sq[i] = s0 + s1;

    if (blockIdx.x == 0) {
        int t = threadIdx.x;
        stats[t] = 0.0f;                               // sum[128], sumsq[128]
        const float4* wp4 = (const float4*)W;
        half8* wh8 = (half8*)Wh;
#pragma unroll
        for (int j = 0; j < 4; ++j) {
            int idx = t * 4 + j;
            float4 a = wp4[2 * idx], b = wp4[2 * idx + 1];
            half8 h;
            h[0] = (_Float16)a.x; h[1] = (_Float16)a.y;
            h[2] = (_Float16)a.z; h[3] = (_Float16)a.w;
            h[4] = (_Float16)b.x; h[5] = (_Float16)b.y;
            h[6] = (_Float16)b.z; h[7] = (_Float16)b.w;
            wh8[idx] = h;
        }
    }
}

// ---------------------------------------------------------------------------
// Kernel 2: MFMA kNN scan (R8-proven: dbuf staging, C=sqn+sqm init, A=-2x,
// Batcher-63 sort + bitonic merge selection, stride-68 key tile).
// ---------------------------------------------------------------------------
__global__ __launch_bounds__(256) void knn_scan_mfma_kernel(
    const _Float16* __restrict__ xh, const _Float16* __restrict__ xh2,
    const float* __restrict__ sq, unsigned* __restrict__ sub_k)
{
    __shared__ _Float16 sBT[2][8][64][8];  // 16 KB dbuf
    __shared__ unsigned s_key[64 * 68];    // 17 KB [row][col] stride 68
    __shared__ float    s_sqm[2][64];

    int blk  = blockIdx.x;
    int tile = blk >> 1;
    int half = blk & 1;
    int b    = tile >> 6;
    int n0   = (tile & 63) * 64;
    int t    = threadIdx.x;
    int l    = t & 63;
    int w    = t >> 6;
    int quad = l >> 4;
    int c16  = l & 15;
    int p    = l;
    int q    = w;

    const _Float16* xhb  = xh  + (size_t)b * NN * CIN;
    const _Float16* xh2b = xh2 + (size_t)b * NN * CIN;
    const float*    sqb  = sq + (size_t)b * NN;

    float sqn_r[4];
#pragma unroll
    for (int r = 0; r < 4; ++r)
        sqn_r[r] = sqb[n0 + 16 * w + 4 * quad + r];

    int row_a = n0 + 16 * w + c16;
    half8 afrag0 = *(const half8*)(xh2b + (size_t)row_a * CIN + 0 * 32 + quad * 8);
    half8 afrag1 = *(const half8*)(xh2b + (size_t)row_a * CIN + 1 * 32 + quad * 8);

    unsigned best[16];
#pragma unroll
    for (int j = 0; j < 16; ++j) best[j] = 0xFFFFFFFFu;

    {
        int cb0 = half * 2048;
#pragma unroll
        for (int r2 = 0; r2 < 2; ++r2) {
            int f = r2 * 256 + t;
            int cand = f >> 3, g = f & 7;
            *(half8*)&sBT[0][g][cand][0] =
                *(const half8*)(xhb + (size_t)(cb0 + cand) * CIN + g * 8);
        }
        if (t < 64) s_sqm[0][t] = sqb[cb0 + t];
    }

#pragma unroll 1
    for (int c = 0; c < 32; ++c) {
        int cur = c & 1;
        int cbase = half * 2048 + c * 64;
        __syncthreads();

        half8 st0, st1; float sqm_n = 0.f;
        int cand0 = t >> 3, g0 = t & 7;
        int cand1 = (256 + t) >> 3, g1 = t & 7;
        bool do_stage = (c < 31);
        if (do_stage) {
            int cb_n = cbase + 64;
            st0 = *(const half8*)(xhb + (size_t)(cb_n + cand0) * CIN + g0 * 8);
            st1 = *(const half8*)(xhb + (size_t)(cb_n + cand1) * CIN + g1 * 8);
            if (t < 64) sqm_n = sqb[cb_n + t];
        }

        f32x4 acc[4];
#pragma unroll
        for (int n = 0; n < 4; ++n) {
            float sm = s_sqm[cur][16 * n + c16];
            f32x4 ci;
            ci[0] = sqn_r[0] + sm; ci[1] = sqn_r[1] + sm;
            ci[2] = sqn_r[2] + sm; ci[3] = sqn_r[3] + sm;
            half8 b0 = *(const half8*)&sBT[cur][0 * 4 + quad][16 * n + c16][0];
            half8 b1 = *(const half8*)&sBT[cur][1 * 4 + quad][16 * n + c16][0];
            ci = __builtin_amdgcn_mfma_f32_16x16x32_f16(afrag0, b0, ci, 0, 0, 0);
            ci = __builtin_amdgcn_mfma_f32_16x16x32_f16(afrag1, b1, ci, 0, 0, 0);
            acc[n] = ci;
        }

        if (do_stage) {
            *(half8*)&sBT[cur ^ 1][g0][cand0][0] = st0;
            *(half8*)&sBT[cur ^ 1][g1][cand1][0] = st1;
            if (t < 64) s_sqm[cur ^ 1][t] = sqm_n;
        }

#pragma unroll
        for (int n = 0; n < 4; ++n) {
            int col = 16 * n + c16;
            unsigned id = (unsigned)(cbase + col);
#pragma unroll
            for (int r = 0; r < 4; ++r) {
                int row = 16 * w + 4 * quad + r;
                float d = fmaxf(acc[n][r], 0.0f);
                s_key[row * 68 + col] = (__float_as_uint(d) & 0xFFFFF000u) | id;
            }
        }
        __syncthreads();

        unsigned a16[16];
#pragma unroll
        for (int j = 0; j < 4; ++j) {
            uint4 v = *(const uint4*)&s_key[p * 68 + q * 16 + 4 * j];
            a16[4 * j + 0] = v.x; a16[4 * j + 1] = v.y;
            a16[4 * j + 2] = v.z; a16[4 * j + 3] = v.w;
        }
        batcher_sort16(a16);
        unsigned m16[16];
#pragma unroll
        for (int i = 0; i < 16; ++i)
            m16[i] = best[i] < a16[15 - i] ? best[i] : a16[15 - i];
#pragma unroll
        for (int d = 8; d > 0; d >>= 1) {
#pragma unroll
            for (int i = 0; i < 16; ++i) {
                if ((i & d) == 0) ce_u32(m16[i], m16[i | d]);
            }
        }
#pragma unroll
        for (int i = 0; i < 16; ++i) best[i] = m16[i];
    }

    size_t base = (((size_t)b * NN + n0 + p) * 8 + half * 4 + q) * 12;
    uint4* dst = (uint4*)(sub_k + base);
    dst[0] = make_uint4(best[0], best[1], best[2],  best[3]);
    dst[1] = make_uint4(best[4], best[5], best[6],  best[7]);
    dst[2] = make_uint4(best[8], best[9], best[10], best[11]);
}

// ---------------------------------------------------------------------------
// Kernel 3: rescue + gather + max-pool + conv MFMA + BN-stats (fused, no grid
// sync). Pool lands in LDS; ph written once for pass 2; conv MFMA reads the
// LDS copy; stats via unioned LDS reduce + 1 atomic/channel. Rescue scratch
// and the stats-reduce scratch are phase-disjoint -> unioned (46 KB total,
// 3 blocks/CU vs R8 rescue's 2).
// ---------------------------------------------------------------------------
__global__ __launch_bounds__(256) void rescue_pool_gemm_stats_kernel(
    const float* __restrict__ x, const _Float16* __restrict__ xh,
    const float* __restrict__ sq, const unsigned* __restrict__ sub_k,
    const _Float16* __restrict__ Wh, const float* __restrict__ bias,
    _Float16* __restrict__ ph, float* __restrict__ stats)
{
    __shared__ union {
        struct {
            unsigned s_pk[4][64][17];            // 17.0 KB
            unsigned short s_cand[64][26];       //  3.3 KB
            unsigned long long s_ek[4][64][6];   // 12.0 KB
        } a;                                     // rescue phases P1-P4a
        struct {
            float s_red[16][130][2];             // 16.6 KB
        } b;                                     // stats phase (after P4a)
    } u;
    __shared__ int s_out[64][KNN];               //  4.0 KB
    __shared__ _Float16 sPH[64][72];             //  9.2 KB (stride 72)
    __shared__ float s_bias[128];                //  0.5 KB

    int blk = blockIdx.x;
    int b   = blk >> 6;
    int n0  = (blk & 63) * 64;
    int t   = threadIdx.x;
    int p   = t & 63;
    int sub = t >> 6;
    int w   = t >> 6, l = t & 63, quad = l >> 4, c16 = l & 15;
    const float*    xb  = x  + (size_t)b * NN * CIN;
    const _Float16* xhb = xh + (size_t)b * NN * CIN;
    const float*    sqb = sq + (size_t)b * NN;
    size_t gp = (size_t)b * NN + n0 + p;

    if (t < 128) s_bias[t] = bias[t];

    // query row in registers
    float xn[CIN];
    {
        const float4* xr = (const float4*)(xb + (size_t)(n0 + p) * CIN);
#pragma unroll
        for (int j = 0; j < CIN / 4; ++j) {
            float4 v = xr[j];
            xn[4 * j + 0] = v.x; xn[4 * j + 1] = v.y;
            xn[4 * j + 2] = v.z; xn[4 * j + 3] = v.w;
        }
    }
    float sqn = sqb[n0 + p];

    // P1: bitonic merge of two sorted-12 streams -> sorted lowest-16 of 24
    {
        const uint4* kp = (const uint4*)(sub_k + gp * 96 + sub * 24);
        uint4 v0 = kp[0], v1 = kp[1], v2 = kp[2];
        uint4 v3 = kp[3], v4 = kp[4], v5 = kp[5];
        unsigned A[16] = { v0.x, v0.y, v0.z, v0.w, v1.x, v1.y, v1.z, v1.w,
                           v2.x, v2.y, v2.z, v2.w,
                           0xFFFFFFFFu, 0xFFFFFFFFu, 0xFFFFFFFFu, 0xFFFFFFFFu };
        unsigned B[16] = { v3.x, v3.y, v3.z, v3.w, v4.x, v4.y, v4.z, v4.w,
                           v5.x, v5.y, v5.z, v5.w,
                           0xFFFFFFFFu, 0xFFFFFFFFu, 0xFFFFFFFFu, 0xFFFFFFFFu };
        unsigned m[16];
#pragma unroll
        for (int i = 0; i < 16; ++i) m[i] = A[i] < B[15 - i] ? A[i] : B[15 - i];
#pragma unroll
        for (int d = 8; d > 0; d >>= 1) {
#pragma unroll
            for (int i = 0; i < 16; ++i) {
                if ((i & d) == 0) ce_u32(m[i], m[i | d]);
            }
        }
#pragma unroll
        for (int j = 0; j < 16; ++j) u.a.s_pk[sub][p][j] = m[j];
    }
    __syncthreads();

    // P2: 4-way merge -> top-24 ids
    if (t < 64) {
        int p0 = 0, p1 = 0, p2 = 0, p3 = 0;
#pragma unroll 1
        for (int k = 0; k < 24; ++k) {
            unsigned k0 = (p0 < 16) ? u.a.s_pk[0][t][p0] : 0xFFFFFFFFu;
            unsigned k1 = (p1 < 16) ? u.a.s_pk[1][t][p1] : 0xFFFFFFFFu;
            unsigned k2 = (p2 < 16) ? u.a.s_pk[2][t][p2] : 0xFFFFFFFFu;
            unsigned k3 = (p3 < 16) ? u.a.s_pk[3][t][p3] : 0xFFFFFFFFu;
            unsigned bk = k0; int bq = 0;
            if (k1 < bk) { bk = k1; bq = 1; }
            if (k2 < bk) { bk = k2; bq = 2; }
            if (k3 < bk) { bk = k3; bq = 3; }
            u.a.s_cand[t][k] = (unsigned short)(bk & 0xFFFu);
            if (bq == 0) ++p0; else if (bq == 1) ++p1; else if (bq == 2) ++p2; else ++p3;
        }
    }
    __syncthreads();

    // P3: exact fp32 distances for 6 ids/thread, reference-faithful 64-bit keys
    {
        unsigned long long b6[6];
#pragma unroll
        for (int j = 0; j < 6; ++j) b6[j] = ~0ULL;
#pragma unroll 1
        for (int j = 0; j < 6; ++j) {
            int m = u.a.s_cand[p][sub * 6 + j];
            const float4* xm4 = (const float4*)(xb + (size_t)m * CIN);
            float d0 = 0.f, d1 = 0.f, d2 = 0.f, d3 = 0.f;
#pragma unroll
            for (int cc = 0; cc < CIN / 4; ++cc) {
                float4 v = xm4[cc];
                d0 = fmaf(xn[4 * cc + 0], v.x, d0);
                d1 = fmaf(xn[4 * cc + 1], v.y, d1);
                d2 = fmaf(xn[4 * cc + 2], v.z, d2);
                d3 = fmaf(xn[4 * cc + 3], v.w, d3);
            }
            float d = sqn + sqb[m] - 2.0f * ((d0 + d1) + (d2 + d3));
            unsigned bbits = __float_as_uint(d);
            unsigned sgn   = (unsigned)((int)bbits >> 31);
            unsigned uu    = bbits ^ (sgn | 0x80000000u);
            unsigned long long cur = ((unsigned long long)uu << 32) | (unsigned)m;
#pragma unroll
            for (int s = 0; s < 6; ++s) {
                unsigned long long lo = cur < b6[s] ? cur : b6[s];
                unsigned long long hi = cur < b6[s] ? b6[s] : cur;
                b6[s] = lo; cur = hi;
            }
        }
#pragma unroll
        for (int j = 0; j < 6; ++j) u.a.s_ek[sub][p][j] = b6[j];
    }
    __syncthreads();

    // P4a: 4-way merge -> exact top-16 ids
    if (t < 64) {
        int p0 = 0, p1 = 0, p2 = 0, p3 = 0;
#pragma unroll 1
        for (int k = 0; k < KNN; ++k) {
            unsigned long long k0 = (p0 < 6) ? u.a.s_ek[0][t][p0] : ~0ULL;
            unsigned long long k1 = (p1 < 6) ? u.a.s_ek[1][t][p1] : ~0ULL;
            unsigned long long k2 = (p2 < 6) ? u.a.s_ek[2][t][p2] : ~0ULL;
            unsigned long long k3 = (p3 < 6) ? u.a.s_ek[3][t][p3] : ~0ULL;
            unsigned long long bk = k0; int bq = 0;
            if (k1 < bk) { bk = k1; bq = 1; }
            if (k2 < bk) { bk = k2; bq = 2; }
            if (k3 < bk) { bk = k3; bq = 3; }
            s_out[t][k] = (int)(bk & 0xFFFu);
            if (bq == 0) ++p0; else if (bq == 1) ++p1; else if (bq == 2) ++p2; else ++p3;
        }
    }
    __syncthreads();                               // last read of union.a done

    // P4b: gather fp16 rows + max-pool -> LDS sPH + global ph (for pass 2)
    {
        int pp = t >> 2;
        int cg = (t & 3) * 16;
        size_t gp2 = (size_t)b * NN + n0 + pp;
        const half8* r0p = (const half8*)(xhb + (size_t)s_out[pp][0] * CIN + cg);
        half8 m0 = r0p[0], m1 = r0p[1];
#pragma unroll 1
        for (int k = 1; k < KNN; ++k) {
            const half8* src = (const half8*)(xhb + (size_t)s_out[pp][k] * CIN + cg);
            half8 v0 = src[0], v1 = src[1];
#pragma unroll
            for (int e = 0; e < 8; ++e) {
                m0[e] = v0[e] > m0[e] ? v0[e] : m0[e];
                m1[e] = v1[e] > m1[e] ? v1[e] : m1[e];
            }
        }
        *(half8*)&sPH[pp][cg]     = m0;
        *(half8*)&sPH[pp][cg + 8] = m1;
        half8* dst = (half8*)(ph + gp2 * CIN + cg);
        dst[0] = m0; dst[1] = m1;
    }
    __syncthreads();

    // conv1x1 MFMA: A from sPH, B = Wh rows (L2-hot)
    half8 a0 = *(const half8*)&sPH[16 * w + c16][quad * 8];
    half8 a1 = *(const half8*)&sPH[16 * w + c16][32 + quad * 8];

    f32x4 acc[8];
#pragma unroll
    for (int n = 0; n < 8; ++n) acc[n] = (f32x4){0.f, 0.f, 0.f, 0.f};
#pragma unroll
    for (int n = 0; n < 8; ++n) {
        const _Float16* wrow = Wh + (size_t)(16 * n + c16) * CIN;
        half8 b0 = *(const half8*)(wrow + quad * 8);
        half8 b1 = *(const half8*)(wrow + 32 + quad * 8);
        acc[n] = __builtin_amdgcn_mfma_f32_16x16x32_f16(a0, b0, acc[n], 0, 0, 0);
        acc[n] = __builtin_amdgcn_mfma_f32_16x16x32_f16(a1, b1, acc[n], 0, 0, 0);
    }
    __syncthreads();                               // union.a dead -> union.b live

    int idx16 = w * 4 + quad;
#pragma unroll
    for (int n = 0; n < 8; ++n) {
        int col = 16 * n + c16;
        float bc = s_bias[col];
        float s = 0.f, s2 = 0.f;
#pragma unroll
        for (int r = 0; r < 4; ++r) {
            float v = acc[n][r] + bc;
            s += v; s2 = fmaf(v, v, s2);
        }
        u.b.s_red[idx16][col][0] = s;
        u.b.s_red[idx16][col][1] = s2;
    }
    __syncthreads();

    if (t < 128) {
        float S = 0.f, S2 = 0.f;
#pragma unroll
        for (int i = 0; i < 16; ++i) { S += u.b.s_red[i][t][0]; S2 += u.b.s_red[i][t][1]; }
        atomicAdd(&stats[t], S);
        atomicAdd(&stats[COUT + t], S2);
    }
}

// ---------------------------------------------------------------------------
// Kernel 4: recompute identical MFMA y, fuse BN + ReLU -> out. (R8-proven)
// ---------------------------------------------------------------------------
__global__ __launch_bounds__(256) void gemm_bn_out_kernel(
    const _Float16* __restrict__ ph, const _Float16* __restrict__ Wh,
    const float* __restrict__ stats, const float* __restrict__ bias,
    const float* __restrict__ gamma, const float* __restrict__ beta,
    float* __restrict__ out)
{
    __shared__ float sS[128];
    __shared__ float sT[128];

    size_t r0 = (size_t)blockIdx.x * 64;
    int t = threadIdx.x;
    int w = t >> 6, l = t & 63, quad = l >> 4, c16 = l & 15;

    if (t < 128) {
        const float invN = 1.0f / (float)NTOT;
        float mean = stats[t] * invN;
        float var  = stats[COUT + t] * invN - mean * mean;
        float S    = gamma[t] * rsqrtf(var + 1e-5f);
        sS[t] = S;
        sT[t] = beta[t] + (bias[t] - mean) * S;
    }

    const _Float16* arow = ph + (r0 + 16 * w + c16) * CIN;
    half8 a0 = *(const half8*)(arow + quad * 8);
    half8 a1 = *(const half8*)(arow + 32 + quad * 8);

    f32x4 acc[8];
#pragma unroll
    for (int n = 0; n < 8; ++n) acc[n] = (f32x4){0.f, 0.f, 0.f, 0.f};
#pragma unroll
    for (int n = 0; n < 8; ++n) {
        const _Float16* wrow = Wh + (size_t)(16 * n + c16) * CIN;
        half8 b0 = *(const half8*)(wrow + quad * 8);
        half8 b1 = *(const half8*)(wrow + 32 + quad * 8);
        acc[n] = __builtin_amdgcn_mfma_f32_16x16x32_f16(a0, b0, acc[n], 0, 0, 0);
        acc[n] = __builtin_amdgcn_mfma_f32_16x16x32_f16(a1, b1, acc[n], 0, 0, 0);
    }
    __syncthreads();

#pragma unroll
    for (int n = 0; n < 8; ++n) {
        int col = 16 * n + c16;
        float Sc = sS[col], Tc = sT[col];
#pragma unroll
        for (int r = 0; r < 4; ++r) {
            int row = 16 * w + quad * 4 + r;
            out[(r0 + row) * COUT + col] = fmaxf(fmaf(acc[n][r], Sc, Tc), 0.0f);
        }
    }
}

// ---------------------------------------------------------------------------
// ws layout (24.25 MiB max; 25 MiB known-safe):
//   [0, 128K)              sq (fp32)
//   [128K, 129K)           stats (sum[128], sumsq[128])
//   [160K, 176K)           Wh (fp16)
//   [256K, 4.25M)          xh  (fp16 x)
//   [4.25M, 8.25M)         xh2 (fp16 -2x)
//   [8.25M, 20.25M)        sub_k (u32, 32768 x 96)
//   [20.25M, 24.25M)       ph (fp16 pooled)
// ---------------------------------------------------------------------------
extern "C" void kernel_launch(void* const* d_in, const int* in_sizes, int n_in,
                              void* d_out, int out_size, void* d_ws, size_t ws_size,
                              hipStream_t stream)
{
    const float* x     = (const float*)d_in[0];
    const float* W     = (const float*)d_in[1];
    const float* bias  = (const float*)d_in[2];
    const float* gamma = (const float*)d_in[3];
    const float* beta  = (const float*)d_in[4];
    float* out = (float*)d_out;

    char* ws = (char*)d_ws;
    float*     sq    = (float*)(ws);
    float*     stats = (float*)(ws + 131072);
    _Float16*  Wh    = (_Float16*)(ws + 163840);
    _Float16*  xh    = (_Float16*)(ws + 262144);
    _Float16*  xh2   = (_Float16*)(ws + 262144 + 4u * 1024 * 1024);
    unsigned*  sub_k = (unsigned*)(ws + 262144 + 8u * 1024 * 1024);
    _Float16*  ph    = (_Float16*)(ws + 262144 + 20u * 1024 * 1024);

    hipLaunchKernelGGL(prep_kernel, dim3(NTOT / 256), dim3(256), 0, stream,
                       x, W, sq, xh, xh2, Wh, stats);
    hipLaunchKernelGGL(knn_scan_mfma_kernel, dim3(NTOT / 64 * 2), dim3(256), 0, stream,
                       xh, xh2, sq, sub_k);
    hipLaunchKernelGGL(rescue_pool_gemm_stats_kernel, dim3(NTOT / 64), dim3(256), 0, stream,
                       x, xh, sq, sub_k, Wh, bias, ph, stats);
    hipLaunchKernelGGL(gemm_bn_out_kernel, dim3(NTOT / 64), dim3(256), 0, stream,
                       ph, Wh, stats, bias, gamma, beta, out);
}

// Round 11
// 235.089 us; speedup vs baseline: 1.3751x; 1.0056x over previous
//
#include <hip/hip_runtime.h>

#define BB   8
#define NN   4096
#define CIN  64
#define COUT 128
#define KNN  16
#define NTOT (BB * NN)

typedef _Float16 half8 __attribute__((ext_vector_type(8)));
typedef float f32x4 __attribute__((ext_vector_type(4)));

__device__ __forceinline__ void ce_u32(unsigned &x, unsigned &y) {
    unsigned lo = x < y ? x : y;
    unsigned hi = x < y ? y : x;
    x = lo; y = hi;
}

// Batcher odd-even mergesort, n=16: 63 CE. All indices compile-time.
__device__ __forceinline__ void batcher_sort16(unsigned a[16]) {
#pragma unroll
    for (int p = 1; p < 16; p <<= 1) {
#pragma unroll
        for (int k = p; k >= 1; k >>= 1) {
#pragma unroll
            for (int j = k & (p - 1); j + k < 16; j += 2 * k) {
#pragma unroll
                for (int i = 0; i < k; ++i) {
                    if (i + j + k < 16 &&
                        (i + j) / (2 * p) == (i + j + k) / (2 * p))
                        ce_u32(a[i + j], a[i + j + k]);
                }
            }
        }
    }
}

// ---------------------------------------------------------------------------
// Kernel 1: per-point sqnorm + fp16 x (xh) + fp16 -2x (xh2). Block 0 converts
// W to fp16 and zeroes BN stats. (R8-proven)
// ---------------------------------------------------------------------------
__global__ __launch_bounds__(256) void prep_kernel(
    const float* __restrict__ x, const float* __restrict__ W,
    float* __restrict__ sq, _Float16* __restrict__ xh,
    _Float16* __restrict__ xh2, _Float16* __restrict__ Wh,
    float* __restrict__ stats)
{
    int i = blockIdx.x * 256 + threadIdx.x;            // point id
    const float4* xr = (const float4*)(x + (size_t)i * CIN);
    half8* xw  = (half8*)(xh  + (size_t)i * CIN);
    half8* xw2 = (half8*)(xh2 + (size_t)i * CIN);
    float s0 = 0.f, s1 = 0.f;
#pragma unroll
    for (int j = 0; j < 8; ++j) {
        float4 a = xr[2 * j], b = xr[2 * j + 1];
        s0 = fmaf(a.x, a.x, s0); s0 = fmaf(a.y, a.y, s0);
        s0 = fmaf(a.z, a.z, s0); s0 = fmaf(a.w, a.w, s0);
        s1 = fmaf(b.x, b.x, s1); s1 = fmaf(b.y, b.y, s1);
        s1 = fmaf(b.z, b.z, s1); s1 = fmaf(b.w, b.w, s1);
        half8 h, h2;
        h[0] = (_Float16)a.x; h[1] = (_Float16)a.y;
        h[2] = (_Float16)a.z; h[3] = (_Float16)a.w;
        h[4] = (_Float16)b.x; h[5] = (_Float16)b.y;
        h[6] = (_Float16)b.z; h[7] = (_Float16)b.w;
#pragma unroll
        for (int e = 0; e < 8; ++e) h2[e] = (_Float16)(-2.0f) * h[e];
        xw[j] = h; xw2[j] = h2;
    }
    sq[i] = s0 + s1;

    if (blockIdx.x == 0) {
        int t = threadIdx.x;
        stats[t] = 0.0f;                               // sum[128], sumsq[128]
        const float4* wp4 = (const float4*)W;
        half8* wh8 = (half8*)Wh;
#pragma unroll
        for (int j = 0; j < 4; ++j) {
            int idx = t * 4 + j;
            float4 a = wp4[2 * idx], b = wp4[2 * idx + 1];
            half8 h;
            h[0] = (_Float16)a.x; h[1] = (_Float16)a.y;
            h[2] = (_Float16)a.z; h[3] = (_Float16)a.w;
            h[4] = (_Float16)b.x; h[5] = (_Float16)b.y;
            h[6] = (_Float16)b.z; h[7] = (_Float16)b.w;
            wh8[idx] = h;
        }
    }
}

// ---------------------------------------------------------------------------
// Kernel 2: MFMA kNN scan (R8-proven structure). __launch_bounds__(256,4):
// LDS (34 KB) caps at 4 blocks/CU = 4 waves/SIMD, so grant the 128-VGPR
// budget that occupancy level allows — VGPR_Count was 52 (8-wave budget the
// LDS cap makes unreachable), starving the 48-reg sort/merge state.
// ---------------------------------------------------------------------------
__global__ __launch_bounds__(256, 4) void knn_scan_mfma_kernel(
    const _Float16* __restrict__ xh, const _Float16* __restrict__ xh2,
    const float* __restrict__ sq, unsigned* __restrict__ sub_k)
{
    __shared__ _Float16 sBT[2][8][64][8];  // 16 KB dbuf
    __shared__ unsigned s_key[64 * 68];    // 17 KB [row][col] stride 68
    __shared__ float    s_sqm[2][64];

    int blk  = blockIdx.x;
    int tile = blk >> 1;
    int half = blk & 1;
    int b    = tile >> 6;
    int n0   = (tile & 63) * 64;
    int t    = threadIdx.x;
    int l    = t & 63;
    int w    = t >> 6;
    int quad = l >> 4;
    int c16  = l & 15;
    int p    = l;
    int q    = w;

    const _Float16* xhb  = xh  + (size_t)b * NN * CIN;
    const _Float16* xh2b = xh2 + (size_t)b * NN * CIN;
    const float*    sqb  = sq + (size_t)b * NN;

    float sqn_r[4];
#pragma unroll
    for (int r = 0; r < 4; ++r)
        sqn_r[r] = sqb[n0 + 16 * w + 4 * quad + r];

    int row_a = n0 + 16 * w + c16;
    half8 afrag0 = *(const half8*)(xh2b + (size_t)row_a * CIN + 0 * 32 + quad * 8);
    half8 afrag1 = *(const half8*)(xh2b + (size_t)row_a * CIN + 1 * 32 + quad * 8);

    unsigned best[16];
#pragma unroll
    for (int j = 0; j < 16; ++j) best[j] = 0xFFFFFFFFu;

    {
        int cb0 = half * 2048;
#pragma unroll
        for (int r2 = 0; r2 < 2; ++r2) {
            int f = r2 * 256 + t;
            int cand = f >> 3, g = f & 7;
            *(half8*)&sBT[0][g][cand][0] =
                *(const half8*)(xhb + (size_t)(cb0 + cand) * CIN + g * 8);
        }
        if (t < 64) s_sqm[0][t] = sqb[cb0 + t];
    }

#pragma unroll 1
    for (int c = 0; c < 32; ++c) {
        int cur = c & 1;
        int cbase = half * 2048 + c * 64;
        __syncthreads();

        half8 st0, st1; float sqm_n = 0.f;
        int cand0 = t >> 3, g0 = t & 7;
        int cand1 = (256 + t) >> 3, g1 = t & 7;
        bool do_stage = (c < 31);
        if (do_stage) {
            int cb_n = cbase + 64;
            st0 = *(const half8*)(xhb + (size_t)(cb_n + cand0) * CIN + g0 * 8);
            st1 = *(const half8*)(xhb + (size_t)(cb_n + cand1) * CIN + g1 * 8);
            if (t < 64) sqm_n = sqb[cb_n + t];
        }

        f32x4 acc[4];
#pragma unroll
        for (int n = 0; n < 4; ++n) {
            float sm = s_sqm[cur][16 * n + c16];
            f32x4 ci;
            ci[0] = sqn_r[0] + sm; ci[1] = sqn_r[1] + sm;
            ci[2] = sqn_r[2] + sm; ci[3] = sqn_r[3] + sm;
            half8 b0 = *(const half8*)&sBT[cur][0 * 4 + quad][16 * n + c16][0];
            half8 b1 = *(const half8*)&sBT[cur][1 * 4 + quad][16 * n + c16][0];
            ci = __builtin_amdgcn_mfma_f32_16x16x32_f16(afrag0, b0, ci, 0, 0, 0);
            ci = __builtin_amdgcn_mfma_f32_16x16x32_f16(afrag1, b1, ci, 0, 0, 0);
            acc[n] = ci;
        }

        if (do_stage) {
            *(half8*)&sBT[cur ^ 1][g0][cand0][0] = st0;
            *(half8*)&sBT[cur ^ 1][g1][cand1][0] = st1;
            if (t < 64) s_sqm[cur ^ 1][t] = sqm_n;
        }

#pragma unroll
        for (int n = 0; n < 4; ++n) {
            int col = 16 * n + c16;
            unsigned id = (unsigned)(cbase + col);
#pragma unroll
            for (int r = 0; r < 4; ++r) {
                int row = 16 * w + 4 * quad + r;
                float d = fmaxf(acc[n][r], 0.0f);
                s_key[row * 68 + col] = (__float_as_uint(d) & 0xFFFFF000u) | id;
            }
        }
        __syncthreads();

        unsigned a16[16];
#pragma unroll
        for (int j = 0; j < 4; ++j) {
            uint4 v = *(const uint4*)&s_key[p * 68 + q * 16 + 4 * j];
            a16[4 * j + 0] = v.x; a16[4 * j + 1] = v.y;
            a16[4 * j + 2] = v.z; a16[4 * j + 3] = v.w;
        }
        batcher_sort16(a16);
        unsigned m16[16];
#pragma unroll
        for (int i = 0; i < 16; ++i)
            m16[i] = best[i] < a16[15 - i] ? best[i] : a16[15 - i];
#pragma unroll
        for (int d = 8; d > 0; d >>= 1) {
#pragma unroll
            for (int i = 0; i < 16; ++i) {
                if ((i & d) == 0) ce_u32(m16[i], m16[i | d]);
            }
        }
#pragma unroll
        for (int i = 0; i < 16; ++i) best[i] = m16[i];
    }

    size_t base = (((size_t)b * NN + n0 + p) * 8 + half * 4 + q) * 12;
    uint4* dst = (uint4*)(sub_k + base);
    dst[0] = make_uint4(best[0], best[1], best[2],  best[3]);
    dst[1] = make_uint4(best[4], best[5], best[6],  best[7]);
    dst[2] = make_uint4(best[8], best[9], best[10], best[11]);
}

// ---------------------------------------------------------------------------
// Kernel 3: rescue + gather + max-pool + conv MFMA + BN-stats (R10-proven).
// __launch_bounds__(256,2): grid (512 blocks) caps at 2 blocks/CU anyway, so
// grant the 256-VGPR budget (xn[64] + sort state no longer spill).
// ---------------------------------------------------------------------------
__global__ __launch_bounds__(256, 2) void rescue_pool_gemm_stats_kernel(
    const float* __restrict__ x, const _Float16* __restrict__ xh,
    const float* __restrict__ sq, const unsigned* __restrict__ sub_k,
    const _Float16* __restrict__ Wh, const float* __restrict__ bias,
    _Float16* __restrict__ ph, float* __restrict__ stats)
{
    __shared__ union {
        struct {
            unsigned s_pk[4][64][17];            // 17.0 KB
            unsigned short s_cand[64][26];       //  3.3 KB
            unsigned long long s_ek[4][64][6];   // 12.0 KB
        } a;                                     // rescue phases P1-P4a
        struct {
            float s_red[16][130][2];             // 16.6 KB
        } b;                                     // stats phase (after P4a)
    } u;
    __shared__ int s_out[64][KNN];               //  4.0 KB
    __shared__ _Float16 sPH[64][72];             //  9.2 KB (stride 72)
    __shared__ float s_bias[128];                //  0.5 KB

    int blk = blockIdx.x;
    int b   = blk >> 6;
    int n0  = (blk & 63) * 64;
    int t   = threadIdx.x;
    int p   = t & 63;
    int sub = t >> 6;
    int w   = t >> 6, l = t & 63, quad = l >> 4, c16 = l & 15;
    const float*    xb  = x  + (size_t)b * NN * CIN;
    const _Float16* xhb = xh + (size_t)b * NN * CIN;
    const float*    sqb = sq + (size_t)b * NN;
    size_t gp = (size_t)b * NN + n0 + p;

    if (t < 128) s_bias[t] = bias[t];

    // query row in registers
    float xn[CIN];
    {
        const float4* xr = (const float4*)(xb + (size_t)(n0 + p) * CIN);
#pragma unroll
        for (int j = 0; j < CIN / 4; ++j) {
            float4 v = xr[j];
            xn[4 * j + 0] = v.x; xn[4 * j + 1] = v.y;
            xn[4 * j + 2] = v.z; xn[4 * j + 3] = v.w;
        }
    }
    float sqn = sqb[n0 + p];

    // P1: bitonic merge of two sorted-12 streams -> sorted lowest-16 of 24
    {
        const uint4* kp = (const uint4*)(sub_k + gp * 96 + sub * 24);
        uint4 v0 = kp[0], v1 = kp[1], v2 = kp[2];
        uint4 v3 = kp[3], v4 = kp[4], v5 = kp[5];
        unsigned A[16] = { v0.x, v0.y, v0.z, v0.w, v1.x, v1.y, v1.z, v1.w,
                           v2.x, v2.y, v2.z, v2.w,
                           0xFFFFFFFFu, 0xFFFFFFFFu, 0xFFFFFFFFu, 0xFFFFFFFFu };
        unsigned B[16] = { v3.x, v3.y, v3.z, v3.w, v4.x, v4.y, v4.z, v4.w,
                           v5.x, v5.y, v5.z, v5.w,
                           0xFFFFFFFFu, 0xFFFFFFFFu, 0xFFFFFFFFu, 0xFFFFFFFFu };
        unsigned m[16];
#pragma unroll
        for (int i = 0; i < 16; ++i) m[i] = A[i] < B[15 - i] ? A[i] : B[15 - i];
#pragma unroll
        for (int d = 8; d > 0; d >>= 1) {
#pragma unroll
            for (int i = 0; i < 16; ++i) {
                if ((i & d) == 0) ce_u32(m[i], m[i | d]);
            }
        }
#pragma unroll
        for (int j = 0; j < 16; ++j) u.a.s_pk[sub][p][j] = m[j];
    }
    __syncthreads();

    // P2: 4-way merge -> top-24 ids
    if (t < 64) {
        int p0 = 0, p1 = 0, p2 = 0, p3 = 0;
#pragma unroll 1
        for (int k = 0; k < 24; ++k) {
            unsigned k0 = (p0 < 16) ? u.a.s_pk[0][t][p0] : 0xFFFFFFFFu;
            unsigned k1 = (p1 < 16) ? u.a.s_pk[1][t][p1] : 0xFFFFFFFFu;
            unsigned k2 = (p2 < 16) ? u.a.s_pk[2][t][p2] : 0xFFFFFFFFu;
            unsigned k3 = (p3 < 16) ? u.a.s_pk[3][t][p3] : 0xFFFFFFFFu;
            unsigned bk = k0; int bq = 0;
            if (k1 < bk) { bk = k1; bq = 1; }
            if (k2 < bk) { bk = k2; bq = 2; }
            if (k3 < bk) { bk = k3; bq = 3; }
            u.a.s_cand[t][k] = (unsigned short)(bk & 0xFFFu);
            if (bq == 0) ++p0; else if (bq == 1) ++p1; else if (bq == 2) ++p2; else ++p3;
        }
    }
    __syncthreads();

    // P3: exact fp32 distances for 6 ids/thread, reference-faithful 64-bit keys
    {
        unsigned long long b6[6];
#pragma unroll
        for (int j = 0; j < 6; ++j) b6[j] = ~0ULL;
#pragma unroll 1
        for (int j = 0; j < 6; ++j) {
            int m = u.a.s_cand[p][sub * 6 + j];
            const float4* xm4 = (const float4*)(xb + (size_t)m * CIN);
            float d0 = 0.f, d1 = 0.f, d2 = 0.f, d3 = 0.f;
#pragma unroll
            for (int cc = 0; cc < CIN / 4; ++cc) {
                float4 v = xm4[cc];
                d0 = fmaf(xn[4 * cc + 0], v.x, d0);
                d1 = fmaf(xn[4 * cc + 1], v.y, d1);
                d2 = fmaf(xn[4 * cc + 2], v.z, d2);
                d3 = fmaf(xn[4 * cc + 3], v.w, d3);
            }
            float d = sqn + sqb[m] - 2.0f * ((d0 + d1) + (d2 + d3));
            unsigned bbits = __float_as_uint(d);
            unsigned sgn   = (unsigned)((int)bbits >> 31);
            unsigned uu    = bbits ^ (sgn | 0x80000000u);
            unsigned long long cur = ((unsigned long long)uu << 32) | (unsigned)m;
#pragma unroll
            for (int s = 0; s < 6; ++s) {
                unsigned long long lo = cur < b6[s] ? cur : b6[s];
                unsigned long long hi = cur < b6[s] ? b6[s] : cur;
                b6[s] = lo; cur = hi;
            }
        }
#pragma unroll
        for (int j = 0; j < 6; ++j) u.a.s_ek[sub][p][j] = b6[j];
    }
    __syncthreads();

    // P4a: 4-way merge -> exact top-16 ids
    if (t < 64) {
        int p0 = 0, p1 = 0, p2 = 0, p3 = 0;
#pragma unroll 1
        for (int k = 0; k < KNN; ++k) {
            unsigned long long k0 = (p0 < 6) ? u.a.s_ek[0][t][p0] : ~0ULL;
            unsigned long long k1 = (p1 < 6) ? u.a.s_ek[1][t][p1] : ~0ULL;
            unsigned long long k2 = (p2 < 6) ? u.a.s_ek[2][t][p2] : ~0ULL;
            unsigned long long k3 = (p3 < 6) ? u.a.s_ek[3][t][p3] : ~0ULL;
            unsigned long long bk = k0; int bq = 0;
            if (k1 < bk) { bk = k1; bq = 1; }
            if (k2 < bk) { bk = k2; bq = 2; }
            if (k3 < bk) { bk = k3; bq = 3; }
            s_out[t][k] = (int)(bk & 0xFFFu);
            if (bq == 0) ++p0; else if (bq == 1) ++p1; else if (bq == 2) ++p2; else ++p3;
        }
    }
    __syncthreads();                               // last read of union.a done

    // P4b: gather fp16 rows + max-pool -> LDS sPH + global ph (for pass 2)
    {
        int pp = t >> 2;
        int cg = (t & 3) * 16;
        size_t gp2 = (size_t)b * NN + n0 + pp;
        const half8* r0p = (const half8*)(xhb + (size_t)s_out[pp][0] * CIN + cg);
        half8 m0 = r0p[0], m1 = r0p[1];
#pragma unroll 1
        for (int k = 1; k < KNN; ++k) {
            const half8* src = (const half8*)(xhb + (size_t)s_out[pp][k] * CIN + cg);
            half8 v0 = src[0], v1 = src[1];
#pragma unroll
            for (int e = 0; e < 8; ++e) {
                m0[e] = v0[e] > m0[e] ? v0[e] : m0[e];
                m1[e] = v1[e] > m1[e] ? v1[e] : m1[e];
            }
        }
        *(half8*)&sPH[pp][cg]     = m0;
        *(half8*)&sPH[pp][cg + 8] = m1;
        half8* dst = (half8*)(ph + gp2 * CIN + cg);
        dst[0] = m0; dst[1] = m1;
    }
    __syncthreads();

    // conv1x1 MFMA: A from sPH, B = Wh rows (L2-hot)
    half8 a0 = *(const half8*)&sPH[16 * w + c16][quad * 8];
    half8 a1 = *(const half8*)&sPH[16 * w + c16][32 + quad * 8];

    f32x4 acc[8];
#pragma unroll
    for (int n = 0; n < 8; ++n) acc[n] = (f32x4){0.f, 0.f, 0.f, 0.f};
#pragma unroll
    for (int n = 0; n < 8; ++n) {
        const _Float16* wrow = Wh + (size_t)(16 * n + c16) * CIN;
        half8 b0 = *(const half8*)(wrow + quad * 8);
        half8 b1 = *(const half8*)(wrow + 32 + quad * 8);
        acc[n] = __builtin_amdgcn_mfma_f32_16x16x32_f16(a0, b0, acc[n], 0, 0, 0);
        acc[n] = __builtin_amdgcn_mfma_f32_16x16x32_f16(a1, b1, acc[n], 0, 0, 0);
    }
    __syncthreads();                               // union.a dead -> union.b live

    int idx16 = w * 4 + quad;
#pragma unroll
    for (int n = 0; n < 8; ++n) {
        int col = 16 * n + c16;
        float bc = s_bias[col];
        float s = 0.f, s2 = 0.f;
#pragma unroll
        for (int r = 0; r < 4; ++r) {
            float v = acc[n][r] + bc;
            s += v; s2 = fmaf(v, v, s2);
        }
        u.b.s_red[idx16][col][0] = s;
        u.b.s_red[idx16][col][1] = s2;
    }
    __syncthreads();

    if (t < 128) {
        float S = 0.f, S2 = 0.f;
#pragma unroll
        for (int i = 0; i < 16; ++i) { S += u.b.s_red[i][t][0]; S2 += u.b.s_red[i][t][1]; }
        atomicAdd(&stats[t], S);
        atomicAdd(&stats[COUT + t], S2);
    }
}

// ---------------------------------------------------------------------------
// Kernel 4: recompute identical MFMA y, fuse BN + ReLU -> out.
// Restructured to 64-thread blocks (one wave = one 16-row tile), grid 2048
// -> 8 blocks/CU (was 512 blocks = 2/CU, grid-limited at 25% occupancy).
// ---------------------------------------------------------------------------
__global__ __launch_bounds__(64, 4) void gemm_bn_out_kernel(
    const _Float16* __restrict__ ph, const _Float16* __restrict__ Wh,
    const float* __restrict__ stats, const float* __restrict__ bias,
    const float* __restrict__ gamma, const float* __restrict__ beta,
    float* __restrict__ out)
{
    __shared__ float sS[128];
    __shared__ float sT[128];

    size_t r0 = (size_t)blockIdx.x * 16;
    int l = threadIdx.x;
    int quad = l >> 4, c16 = l & 15;

    {
        const float invN = 1.0f / (float)NTOT;
#pragma unroll
        for (int h = 0; h < 2; ++h) {
            int ch = l + 64 * h;
            float mean = stats[ch] * invN;
            float var  = stats[COUT + ch] * invN - mean * mean;
            float S    = gamma[ch] * rsqrtf(var + 1e-5f);
            sS[ch] = S;
            sT[ch] = beta[ch] + (bias[ch] - mean) * S;
        }
    }

    const _Float16* arow = ph + (r0 + c16) * CIN;
    half8 a0 = *(const half8*)(arow + quad * 8);
    half8 a1 = *(const half8*)(arow + 32 + quad * 8);

    f32x4 acc[8];
#pragma unroll
    for (int n = 0; n < 8; ++n) acc[n] = (f32x4){0.f, 0.f, 0.f, 0.f};
#pragma unroll
    for (int n = 0; n < 8; ++n) {
        const _Float16* wrow = Wh + (size_t)(16 * n + c16) * CIN;
        half8 b0 = *(const half8*)(wrow + quad * 8);
        half8 b1 = *(const half8*)(wrow + 32 + quad * 8);
        acc[n] = __builtin_amdgcn_mfma_f32_16x16x32_f16(a0, b0, acc[n], 0, 0, 0);
        acc[n] = __builtin_amdgcn_mfma_f32_16x16x32_f16(a1, b1, acc[n], 0, 0, 0);
    }
    __syncthreads();

#pragma unroll
    for (int n = 0; n < 8; ++n) {
        int col = 16 * n + c16;
        float Sc = sS[col], Tc = sT[col];
#pragma unroll
        for (int r = 0; r < 4; ++r) {
            int row = quad * 4 + r;
            out[(r0 + row) * COUT + col] = fmaxf(fmaf(acc[n][r], Sc, Tc), 0.0f);
        }
    }
}

// ---------------------------------------------------------------------------
// ws layout (24.25 MiB max; 25 MiB known-safe):
//   [0, 128K)              sq (fp32)
//   [128K, 129K)           stats (sum[128], sumsq[128])
//   [160K, 176K)           Wh (fp16)
//   [256K, 4.25M)          xh  (fp16 x)
//   [4.25M, 8.25M)         xh2 (fp16 -2x)
//   [8.25M, 20.25M)        sub_k (u32, 32768 x 96)
//   [20.25M, 24.25M)       ph (fp16 pooled)
// ---------------------------------------------------------------------------
extern "C" void kernel_launch(void* const* d_in, const int* in_sizes, int n_in,
                              void* d_out, int out_size, void* d_ws, size_t ws_size,
                              hipStream_t stream)
{
    const float* x     = (const float*)d_in[0];
    const float* W     = (const float*)d_in[1];
    const float* bias  = (const float*)d_in[2];
    const float* gamma = (const float*)d_in[3];
    const float* beta  = (const float*)d_in[4];
    float* out = (float*)d_out;

    char* ws = (char*)d_ws;
    float*     sq    = (float*)(ws);
    float*     stats = (float*)(ws + 131072);
    _Float16*  Wh    = (_Float16*)(ws + 163840);
    _Float16*  xh    = (_Float16*)(ws + 262144);
    _Float16*  xh2   = (_Float16*)(ws + 262144 + 4u * 1024 * 1024);
    unsigned*  sub_k = (unsigned*)(ws + 262144 + 8u * 1024 * 1024);
    _Float16*  ph    = (_Float16*)(ws + 262144 + 20u * 1024 * 1024);

    hipLaunchKernelGGL(prep_kernel, dim3(NTOT / 256), dim3(256), 0, stream,
                       x, W, sq, xh, xh2, Wh, stats);
    hipLaunchKernelGGL(knn_scan_mfma_kernel, dim3(NTOT / 64 * 2), dim3(256), 0, stream,
                       xh, xh2, sq, sub_k);
    hipLaunchKernelGGL(rescue_pool_gemm_stats_kernel, dim3(NTOT / 64), dim3(256), 0, stream,
                       x, xh, sq, sub_k, Wh, bias, ph, stats);
    hipLaunchKernelGGL(gemm_bn_out_kernel, dim3(NTOT / 16), dim3(64), 0, stream,
                       ph, Wh, stats, bias, gamma, beta, out);
}